// Round 3
// baseline (7524.125 us; speedup 1.0000x reference)
//
#include <hip/hip_runtime.h>
#include <cstdint>

// ---------------- problem constants ----------------
#define SEQL     2560     // 4*20*32
#define DIMC     2048
#define NHEADS   16
#define HD       128
#define FFND     8192
#define CTXD     4096
#define CTXL     512
#define LN_EPS   1e-6f
#define ATTN_SCALE 0.08838834764831845f  // 128^-0.5

// ---------------- helpers ----------------
__device__ __forceinline__ float block_reduce_sum(float v, float* buf) {
  #pragma unroll
  for (int o = 32; o > 0; o >>= 1) v += __shfl_xor(v, o, 64);
  __syncthreads();                    // protect buf from previous use
  if ((threadIdx.x & 63) == 0) buf[threadIdx.x >> 6] = v;
  __syncthreads();
  return buf[0] + buf[1] + buf[2] + buf[3];
}

__device__ __forceinline__ float gelu_tanh(float x) {
  float x3 = x * x * x;
  return 0.5f * x * (1.0f + tanhf(0.7978845608028654f * (x + 0.044715f * x3)));
}

// ---------------- tiny prep kernels ----------------
__global__ void em_kernel(const float* __restrict__ e, const float* __restrict__ mod,
                          float* __restrict__ em) {
  int g = blockIdx.x * 256 + threadIdx.x;   // 6*2048 = 12288
  if (g < 6 * DIMC) em[g] = e[g] + mod[g];
}

// cos/sin table: cs[(s*64 + i)*2] = cos(ang), +1 = sin(ang); i = pair index 0..63
__global__ void cs_kernel(const float* __restrict__ af, const float* __restrict__ ah,
                          const float* __restrict__ aw, float* __restrict__ cs) {
  int g = blockIdx.x * 256 + threadIdx.x;   // 2560*64
  if (g >= SEQL * 64) return;
  int s = g >> 6, i = g & 63;
  int fi = s / 640, rem = s % 640, hi = rem >> 5, wi = rem & 31;
  float ang;
  if (i < 22)       ang = af[fi * 22 + i];          // cf = 22
  else if (i < 43)  ang = ah[hi * 21 + (i - 22)];   // ch = 21
  else              ang = aw[wi * 21 + (i - 43)];   // cw = 21
  cs[2 * g]     = cosf(ang);
  cs[2 * g + 1] = sinf(ang);
}

// ---------------- LayerNorm: y = LN(x) * (avec [+1]) + bvec ----------------
__global__ __launch_bounds__(256) void ln_kernel(const float* __restrict__ x,
    float* __restrict__ y, const float* __restrict__ avec,
    const float* __restrict__ bvec, int addone) {
  __shared__ float buf[8];
  const int row = blockIdx.x, tid = threadIdx.x;
  const float* xr = x + (size_t)row * DIMC;
  float4 v0 = *(const float4*)&xr[4 * tid];
  float4 v1 = *(const float4*)&xr[1024 + 4 * tid];
  float s = v0.x + v0.y + v0.z + v0.w + v1.x + v1.y + v1.z + v1.w;
  s = block_reduce_sum(s, buf);
  float mean = s * (1.0f / 2048.0f);
  float d0x = v0.x - mean, d0y = v0.y - mean, d0z = v0.z - mean, d0w = v0.w - mean;
  float d1x = v1.x - mean, d1y = v1.y - mean, d1z = v1.z - mean, d1w = v1.w - mean;
  float ss = d0x*d0x + d0y*d0y + d0z*d0z + d0w*d0w
           + d1x*d1x + d1y*d1y + d1z*d1z + d1w*d1w;
  ss = block_reduce_sum(ss, buf);
  float rstd = rsqrtf(ss * (1.0f / 2048.0f) + LN_EPS);
  float add = addone ? 1.0f : 0.0f;
  float4 a0 = *(const float4*)&avec[4 * tid];
  float4 a1 = *(const float4*)&avec[1024 + 4 * tid];
  float4 b0 = *(const float4*)&bvec[4 * tid];
  float4 b1 = *(const float4*)&bvec[1024 + 4 * tid];
  float4 o0, o1;
  o0.x = d0x * rstd * (a0.x + add) + b0.x;
  o0.y = d0y * rstd * (a0.y + add) + b0.y;
  o0.z = d0z * rstd * (a0.z + add) + b0.z;
  o0.w = d0w * rstd * (a0.w + add) + b0.w;
  o1.x = d1x * rstd * (a1.x + add) + b1.x;
  o1.y = d1y * rstd * (a1.y + add) + b1.y;
  o1.z = d1z * rstd * (a1.z + add) + b1.z;
  o1.w = d1w * rstd * (a1.w + add) + b1.w;
  float* yr = y + (size_t)row * DIMC;
  *(float4*)&yr[4 * tid] = o0;
  *(float4*)&yr[1024 + 4 * tid] = o1;
}

// ---------------- RMSNorm (in-place) + optional RoPE ----------------
__global__ __launch_bounds__(256) void rms_rope_kernel(float* __restrict__ q,
    const float* __restrict__ wv, const float* __restrict__ cs, int do_rope) {
  __shared__ float buf[8];
  const int row = blockIdx.x, tid = threadIdx.x;
  float* xr = q + (size_t)row * DIMC;
  float4 v0 = *(float4*)&xr[4 * tid];
  float4 v1 = *(float4*)&xr[1024 + 4 * tid];
  float ss = v0.x*v0.x + v0.y*v0.y + v0.z*v0.z + v0.w*v0.w
           + v1.x*v1.x + v1.y*v1.y + v1.z*v1.z + v1.w*v1.w;
  ss = block_reduce_sum(ss, buf);
  float rr = rsqrtf(ss * (1.0f / 2048.0f) + LN_EPS);
  float4 w0 = *(const float4*)&wv[4 * tid];
  float4 w1 = *(const float4*)&wv[1024 + 4 * tid];
  v0.x *= rr * w0.x; v0.y *= rr * w0.y; v0.z *= rr * w0.z; v0.w *= rr * w0.w;
  v1.x *= rr * w1.x; v1.y *= rr * w1.y; v1.z *= rr * w1.z; v1.w *= rr * w1.w;
  if (do_rope) {
    // cols 4t..4t+3 -> pair indices (2t)&63, (2t+1)&63 ; col 1024+4t -> same (1024 = 8*128)
    int i0 = (2 * tid) & 63, i1 = (2 * tid + 1) & 63;
    float2 cs0 = *(const float2*)&cs[(size_t)(row * 64 + i0) * 2];
    float2 cs1 = *(const float2*)&cs[(size_t)(row * 64 + i1) * 2];
    float e, o;
    e = v0.x; o = v0.y; v0.x = e*cs0.x - o*cs0.y; v0.y = e*cs0.y + o*cs0.x;
    e = v0.z; o = v0.w; v0.z = e*cs1.x - o*cs1.y; v0.w = e*cs1.y + o*cs1.x;
    e = v1.x; o = v1.y; v1.x = e*cs0.x - o*cs0.y; v1.y = e*cs0.y + o*cs0.x;
    e = v1.z; o = v1.w; v1.z = e*cs1.x - o*cs1.y; v1.w = e*cs1.y + o*cs1.x;
  }
  *(float4*)&xr[4 * tid] = v0;
  *(float4*)&xr[1024 + 4 * tid] = v1;
}

// ---------------- fp32 tiled GEMM: C = epilogue(A[MxK] @ W[KxN]) ----------------
// MODE 0: C = acc + bias
// MODE 1: C = gelu(acc + bias)
// MODE 2: C = res + (acc + bias) * evec
// MODE 3: C = res + (acc + bias)
// MODE 4: C = C + acc * evec          (split-K accumulate)
template<int MODE>
__global__ __launch_bounds__(256) void gemm_kernel(
    const float* __restrict__ A, const float* __restrict__ W,
    const float* __restrict__ bias, const float* __restrict__ res,
    const float* __restrict__ evec, float* __restrict__ C,
    int M, int N, int K, int lda, int ldw, int ldc) {
  __shared__ float As[16][132];   // A tile transposed [k][m], pad 4 -> write 2-way, read free
  __shared__ float Ws[16][68];    // W tile [k][n], pad 4 -> float4-aligned, read 2-way
  const int tid = threadIdx.x;
  const int ty = tid >> 4, tx = tid & 15;
  const int m0 = blockIdx.y * 128;
  const int n0 = blockIdx.x * 64;

  float acc[8][4];
  #pragma unroll
  for (int i = 0; i < 8; ++i)
    #pragma unroll
    for (int j = 0; j < 4; ++j) acc[i][j] = 0.0f;

  const int ar = tid >> 2;            // 0..63
  const int aq = (tid & 3) * 4;       // k sub-offset 0,4,8,12
  const int wr = tid >> 4;            // 0..15
  const int wf = (tid & 15) * 4;      // 0..60

  for (int k0 = 0; k0 < K; k0 += 16) {
    __syncthreads();
    #pragma unroll
    for (int p = 0; p < 2; ++p) {
      const int r = ar + p * 64;
      float4 a = *(const float4*)&A[(size_t)(m0 + r) * lda + k0 + aq];
      As[aq + 0][r] = a.x;
      As[aq + 1][r] = a.y;
      As[aq + 2][r] = a.z;
      As[aq + 3][r] = a.w;
    }
    {
      float4 w = *(const float4*)&W[(size_t)(k0 + wr) * ldw + n0 + wf];
      *(float4*)&Ws[wr][wf] = w;
    }
    __syncthreads();
    #pragma unroll
    for (int kk = 0; kk < 16; ++kk) {
      float4 a0 = *(const float4*)&As[kk][ty * 8];
      float4 a1 = *(const float4*)&As[kk][ty * 8 + 4];
      float4 w0 = *(const float4*)&Ws[kk][tx * 4];
      float av[8] = {a0.x, a0.y, a0.z, a0.w, a1.x, a1.y, a1.z, a1.w};
      float wvv[4] = {w0.x, w0.y, w0.z, w0.w};
      #pragma unroll
      for (int i = 0; i < 8; ++i)
        #pragma unroll
        for (int j = 0; j < 4; ++j)
          acc[i][j] = fmaf(av[i], wvv[j], acc[i][j]);
    }
  }

  // epilogue
  float bv[4] = {0.f, 0.f, 0.f, 0.f};
  float ev[4] = {0.f, 0.f, 0.f, 0.f};
  if constexpr (MODE != 4) {
    float4 b = *(const float4*)&bias[n0 + tx * 4];
    bv[0] = b.x; bv[1] = b.y; bv[2] = b.z; bv[3] = b.w;
  }
  if constexpr (MODE == 2 || MODE == 4) {
    float4 e4 = *(const float4*)&evec[n0 + tx * 4];
    ev[0] = e4.x; ev[1] = e4.y; ev[2] = e4.z; ev[3] = e4.w;
  }
  #pragma unroll
  for (int i = 0; i < 8; ++i) {
    const size_t off = (size_t)(m0 + ty * 8 + i) * ldc + n0 + tx * 4;
    float v[4];
    #pragma unroll
    for (int j = 0; j < 4; ++j) v[j] = acc[i][j];
    if constexpr (MODE != 4) {
      #pragma unroll
      for (int j = 0; j < 4; ++j) v[j] += bv[j];
    }
    if constexpr (MODE == 1) {
      #pragma unroll
      for (int j = 0; j < 4; ++j) v[j] = gelu_tanh(v[j]);
    }
    if constexpr (MODE == 2) {
      float4 r = *(const float4*)&res[off];
      float rr[4] = {r.x, r.y, r.z, r.w};
      #pragma unroll
      for (int j = 0; j < 4; ++j) v[j] = rr[j] + v[j] * ev[j];
    }
    if constexpr (MODE == 3) {
      float4 r = *(const float4*)&res[off];
      float rr[4] = {r.x, r.y, r.z, r.w};
      #pragma unroll
      for (int j = 0; j < 4; ++j) v[j] = rr[j] + v[j];
    }
    if constexpr (MODE == 4) {
      float4 c4 = *(const float4*)&C[off];
      float cc[4] = {c4.x, c4.y, c4.z, c4.w};
      #pragma unroll
      for (int j = 0; j < 4; ++j) v[j] = cc[j] + v[j] * ev[j];
    }
    float4 o4 = {v[0], v[1], v[2], v[3]};
    *(float4*)&C[off] = o4;
  }
}

// ---------------- flash attention, fp32 ----------------
// Q,K,V,O laid out (S, HEADS*HD) contiguous; per block: 64 q rows x 1 head.
// KV tiles of 32 rows. K staged transposed in LDS; V streamed from global (L2-hot).
__global__ __launch_bounds__(256) void attn_kernel(
    const float* __restrict__ Q, const float* __restrict__ K,
    const float* __restrict__ V, float* __restrict__ O, int Skv) {
  __shared__ float Qs[64][132];   // 33792 B, pad 4 -> float4 k-reads aligned & conflict-lite
  __shared__ float Ks[128][33];   // 16896 B, [k][j], odd pad -> conflict-free reads
  __shared__ float Ss[64][33];    //  8448 B
  __shared__ float mS[64], lS[64], aS[64];

  const int tid = threadIdx.x;
  const int ty = tid >> 4, tx = tid & 15;
  const int q0 = blockIdx.x * 64;
  const int cb = blockIdx.y * HD;   // head col base

  #pragma unroll
  for (int p = 0; p < 8; ++p) {
    int idx = tid + p * 256;
    int r = idx >> 5, f = idx & 31;
    float4 v = *(const float4*)&Q[(size_t)(q0 + r) * DIMC + cb + 4 * f];
    v.x *= ATTN_SCALE; v.y *= ATTN_SCALE; v.z *= ATTN_SCALE; v.w *= ATTN_SCALE;
    *(float4*)&Qs[r][4 * f] = v;
  }
  if (tid < 64) { mS[tid] = -3.0e38f; lS[tid] = 0.0f; }

  float oacc[4][8];
  #pragma unroll
  for (int i = 0; i < 4; ++i)
    #pragma unroll
    for (int c = 0; c < 8; ++c) oacc[i][c] = 0.0f;

  for (int kv0 = 0; kv0 < Skv; kv0 += 32) {
    __syncthreads();   // prev PV done -> safe to overwrite Ks/Ss
    #pragma unroll
    for (int p = 0; p < 4; ++p) {
      int idx = tid + p * 256;
      int r = idx >> 5, f = idx & 31;
      float4 kv = *(const float4*)&K[(size_t)(kv0 + r) * DIMC + cb + 4 * f];
      Ks[4 * f + 0][r] = kv.x;
      Ks[4 * f + 1][r] = kv.y;
      Ks[4 * f + 2][r] = kv.z;
      Ks[4 * f + 3][r] = kv.w;
    }
    __syncthreads();

    // S tile: rows ty*4+i, cols tx*2+jj
    float sacc[4][2];
    #pragma unroll
    for (int i = 0; i < 4; ++i) { sacc[i][0] = 0.f; sacc[i][1] = 0.f; }
    #pragma unroll 2
    for (int k4 = 0; k4 < 128; k4 += 4) {
      float qa[4][4];
      #pragma unroll
      for (int i = 0; i < 4; ++i) {
        float4 t = *(const float4*)&Qs[ty * 4 + i][k4];
        qa[i][0] = t.x; qa[i][1] = t.y; qa[i][2] = t.z; qa[i][3] = t.w;
      }
      #pragma unroll
      for (int u = 0; u < 4; ++u) {
        float kv0v = Ks[k4 + u][tx * 2];
        float kv1v = Ks[k4 + u][tx * 2 + 1];
        #pragma unroll
        for (int i = 0; i < 4; ++i) {
          sacc[i][0] = fmaf(qa[i][u], kv0v, sacc[i][0]);
          sacc[i][1] = fmaf(qa[i][u], kv1v, sacc[i][1]);
        }
      }
    }
    #pragma unroll
    for (int i = 0; i < 4; ++i) {
      Ss[ty * 4 + i][tx * 2]     = sacc[i][0];
      Ss[ty * 4 + i][tx * 2 + 1] = sacc[i][1];
    }
    __syncthreads();

    // online softmax: one thread per q row
    if (tid < 64) {
      float mo = mS[tid];
      float pm = mo;
      #pragma unroll 4
      for (int j = 0; j < 32; ++j) pm = fmaxf(pm, Ss[tid][j]);
      float alpha = __expf(mo - pm);
      float sum = 0.0f;
      #pragma unroll 4
      for (int j = 0; j < 32; ++j) {
        float p = __expf(Ss[tid][j] - pm);
        Ss[tid][j] = p;
        sum += p;
      }
      lS[tid] = lS[tid] * alpha + sum;
      mS[tid] = pm;
      aS[tid] = alpha;
    }
    __syncthreads();

    // rescale O and accumulate P @ V (V from global: tile is L2-resident)
    float al[4];
    #pragma unroll
    for (int i = 0; i < 4; ++i) al[i] = aS[ty * 4 + i];
    #pragma unroll
    for (int i = 0; i < 4; ++i)
      #pragma unroll
      for (int c = 0; c < 8; ++c) oacc[i][c] *= al[i];
    #pragma unroll 4
    for (int j = 0; j < 32; ++j) {
      const float* vrow = &V[(size_t)(kv0 + j) * DIMC + cb + tx * 8];
      float4 va = *(const float4*)vrow;
      float4 vb = *(const float4*)(vrow + 4);
      float vv[8] = {va.x, va.y, va.z, va.w, vb.x, vb.y, vb.z, vb.w};
      float pv[4] = {Ss[ty * 4 + 0][j], Ss[ty * 4 + 1][j],
                     Ss[ty * 4 + 2][j], Ss[ty * 4 + 3][j]};
      #pragma unroll
      for (int i = 0; i < 4; ++i)
        #pragma unroll
        for (int c = 0; c < 8; ++c)
          oacc[i][c] = fmaf(pv[i], vv[c], oacc[i][c]);
    }
  }

  #pragma unroll
  for (int i = 0; i < 4; ++i) {
    float inv = 1.0f / lS[ty * 4 + i];
    float4 oa = {oacc[i][0] * inv, oacc[i][1] * inv, oacc[i][2] * inv, oacc[i][3] * inv};
    float4 ob = {oacc[i][4] * inv, oacc[i][5] * inv, oacc[i][6] * inv, oacc[i][7] * inv};
    float* orow = &O[(size_t)(q0 + ty * 4 + i) * DIMC + cb + tx * 8];
    *(float4*)orow = oa;
    *(float4*)(orow + 4) = ob;
  }
}

// ---------------- host side ----------------
static inline void gemm_launch(int mode, const float* A, const float* W,
    const float* bias, const float* res, const float* evec, float* C,
    int M, int N, int K, int lda, int ldw, int ldc, hipStream_t s) {
  dim3 grid(N / 64, M / 128), blk(256);
  switch (mode) {
    case 0: gemm_kernel<0><<<grid, blk, 0, s>>>(A, W, bias, res, evec, C, M, N, K, lda, ldw, ldc); break;
    case 1: gemm_kernel<1><<<grid, blk, 0, s>>>(A, W, bias, res, evec, C, M, N, K, lda, ldw, ldc); break;
    case 2: gemm_kernel<2><<<grid, blk, 0, s>>>(A, W, bias, res, evec, C, M, N, K, lda, ldw, ldc); break;
    case 3: gemm_kernel<3><<<grid, blk, 0, s>>>(A, W, bias, res, evec, C, M, N, K, lda, ldw, ldc); break;
    case 4: gemm_kernel<4><<<grid, blk, 0, s>>>(A, W, bias, res, evec, C, M, N, K, lda, ldw, ldc); break;
  }
}

extern "C" void kernel_launch(void* const* d_in, const int* in_sizes, int n_in,
                              void* d_out, int out_size, void* d_ws, size_t ws_size,
                              hipStream_t stream) {
  const float* x     = (const float*)d_in[0];
  const float* e     = (const float*)d_in[1];
  const float* ctx   = (const float*)d_in[2];
  // d_in[3..5] = f,h,w scalars (compile-time constants here)
  const float* q_w   = (const float*)d_in[6];
  const float* q_b   = (const float*)d_in[7];
  const float* k_w   = (const float*)d_in[8];
  const float* k_b   = (const float*)d_in[9];
  const float* v_w   = (const float*)d_in[10];
  const float* v_b   = (const float*)d_in[11];
  const float* o_w   = (const float*)d_in[12];
  const float* o_b   = (const float*)d_in[13];
  const float* nq_w  = (const float*)d_in[14];
  const float* nk_w  = (const float*)d_in[15];
  const float* cq_w  = (const float*)d_in[16];
  const float* cq_b  = (const float*)d_in[17];
  const float* ck_w  = (const float*)d_in[18];
  const float* ck_b  = (const float*)d_in[19];
  const float* cv_w  = (const float*)d_in[20];
  const float* cv_b  = (const float*)d_in[21];
  const float* co_w  = (const float*)d_in[22];
  const float* co_b  = (const float*)d_in[23];
  const float* cnq_w = (const float*)d_in[24];
  const float* cnk_w = (const float*)d_in[25];
  const float* n3g   = (const float*)d_in[26];
  const float* n3b   = (const float*)d_in[27];
  const float* w1    = (const float*)d_in[28];
  const float* b1    = (const float*)d_in[29];
  const float* w2    = (const float*)d_in[30];
  const float* b2    = (const float*)d_in[31];
  const float* mod   = (const float*)d_in[32];
  const float* ang_f = (const float*)d_in[33];
  const float* ang_h = (const float*)d_in[34];
  const float* ang_w = (const float*)d_in[35];
  float* out = (float*)d_out;

  // workspace layout (floats) — B7 (FFN hidden chunk) aliases B3 (cq, dead by then)
  const size_t SZ_BIG = (size_t)SEQL * DIMC;   // 5,242,880
  const size_t SZ_CTX = (size_t)CTXL * DIMC;   // 1,048,576
  float* ws  = (float*)d_ws;
  float* em  = ws;                    // 6*2048
  float* cs  = em + 6 * DIMC;         // 2560*64*2
  float* B0  = cs + (size_t)SEQL * 128;
  float* B1  = B0 + SZ_BIG;
  float* B2  = B1 + SZ_BIG;
  float* B3  = B2 + SZ_BIG;
  float* B5  = B3 + SZ_BIG;
  float* B6  = B5 + SZ_CTX;
  float* B7  = B3;                    // alias: FFN hidden chunk reuses cq buffer
  const size_t need = (size_t)(B6 + SZ_CTX - ws) * sizeof(float);  // ~93.4 MB
  if (ws_size < need) return;         // fail fast (validation will flag it)

  const float* e0 = em + 0 * DIMC;
  const float* e1 = em + 1 * DIMC;
  const float* e2 = em + 2 * DIMC;
  const float* e3 = em + 3 * DIMC;
  const float* e4 = em + 4 * DIMC;
  const float* e5 = em + 5 * DIMC;

  em_kernel<<<48, 256, 0, stream>>>(e, mod, em);
  cs_kernel<<<640, 256, 0, stream>>>(ang_f, ang_h, ang_w, cs);

  // y = LN(x)*(1+e1)+e0
  ln_kernel<<<SEQL, 256, 0, stream>>>(x, B0, e1, e0, 1);

  // QKV projections
  gemm_launch(0, B0, q_w, q_b, nullptr, nullptr, B1, SEQL, DIMC, DIMC, DIMC, DIMC, DIMC, stream);
  gemm_launch(0, B0, k_w, k_b, nullptr, nullptr, B2, SEQL, DIMC, DIMC, DIMC, DIMC, DIMC, stream);
  gemm_launch(0, B0, v_w, v_b, nullptr, nullptr, B3, SEQL, DIMC, DIMC, DIMC, DIMC, DIMC, stream);

  // rmsnorm + rope on q,k
  rms_rope_kernel<<<SEQL, 256, 0, stream>>>(B1, nq_w, cs, 1);
  rms_rope_kernel<<<SEQL, 256, 0, stream>>>(B2, nk_w, cs, 1);

  // self attention -> B0
  attn_kernel<<<dim3(SEQL / 64, NHEADS), 256, 0, stream>>>(B1, B2, B3, B0, SEQL);

  // x2 = x + (a @ o_w + o_b) * e2   -> B1
  gemm_launch(2, B0, o_w, o_b, x, e2, B1, SEQL, DIMC, DIMC, DIMC, DIMC, DIMC, stream);

  // cx = LN(x2, g, b) -> B2
  ln_kernel<<<SEQL, 256, 0, stream>>>(B1, B2, n3g, n3b, 0);

  // cq -> B3 (rmsnorm, no rope)
  gemm_launch(0, B2, cq_w, cq_b, nullptr, nullptr, B3, SEQL, DIMC, DIMC, DIMC, DIMC, DIMC, stream);
  rms_rope_kernel<<<SEQL, 256, 0, stream>>>(B3, cnq_w, cs, 0);

  // ck, cv from context -> B5, B6
  gemm_launch(0, ctx, ck_w, ck_b, nullptr, nullptr, B5, CTXL, DIMC, CTXD, CTXD, DIMC, DIMC, stream);
  rms_rope_kernel<<<CTXL, 256, 0, stream>>>(B5, cnk_w, cs, 0);
  gemm_launch(0, ctx, cv_w, cv_b, nullptr, nullptr, B6, CTXL, DIMC, CTXD, CTXD, DIMC, DIMC, stream);

  // cross attention -> B0
  attn_kernel<<<dim3(SEQL / 64, NHEADS), 256, 0, stream>>>(B3, B5, B6, B0, CTXL);

  // x3 = x2 + (ca @ co_w + co_b)   -> B2
  gemm_launch(3, B0, co_w, co_b, B1, nullptr, B2, SEQL, DIMC, DIMC, DIMC, DIMC, DIMC, stream);

  // y3 = LN(x3)*(1+e4)+e3 -> B0
  ln_kernel<<<SEQL, 256, 0, stream>>>(B2, B0, e4, e3, 1);

  // FFN, hidden chunked 4 x 2048 with split-K accumulation into out
  // (B7 == B3: cq is dead after cross-attention; x3 in B2 is read only in chunk 0)
  for (int c = 0; c < 4; ++c) {
    const float* w1c = w1 + (size_t)c * 2048;            // column chunk, ldw = 8192
    const float* b1c = b1 + (size_t)c * 2048;
    const float* w2c = w2 + (size_t)c * 2048 * DIMC;     // row chunk, ldw = 2048
    gemm_launch(1, B0, w1c, b1c, nullptr, nullptr, B7, SEQL, 2048, DIMC, DIMC, FFND, 2048, stream);
    if (c == 0)
      gemm_launch(2, B7, w2c, b2, B2, e5, out, SEQL, DIMC, 2048, 2048, DIMC, DIMC, stream);
    else
      gemm_launch(4, B7, w2c, nullptr, nullptr, e5, out, SEQL, DIMC, 2048, 2048, DIMC, DIMC, stream);
  }
}

// Round 4
// 3486.899 us; speedup vs baseline: 2.1578x; 2.1578x over previous
//
#include <hip/hip_runtime.h>
#include <cstdint>

// ---------------- problem constants ----------------
#define SEQL     2560     // 4*20*32
#define DIMC     2048
#define NHEADS   16
#define HD       128
#define FFND     8192
#define CTXD     4096
#define CTXL     512
#define LN_EPS   1e-6f
#define ATTN_SCALE 0.08838834764831845f  // 128^-0.5

typedef __attribute__((ext_vector_type(8))) short bfx8;   // MFMA A/B frag (8 bf16)
typedef __attribute__((ext_vector_type(4))) short bfx4;
typedef __attribute__((ext_vector_type(4))) float fx4;    // MFMA C/D frag

// ---------------- helpers ----------------
__device__ __forceinline__ float bf2f(ushort h) {
  union { uint u; float f; } c; c.u = ((uint)h) << 16; return c.f;
}
__device__ __forceinline__ ushort f2bf(float f) {
  union { float f; uint u; } c; c.f = f;
  uint u = c.u;
  return (ushort)((u + 0x7FFFu + ((u >> 16) & 1u)) >> 16);   // RNE
}
__device__ __forceinline__ float block_reduce_sum(float v, float* buf) {
  #pragma unroll
  for (int o = 32; o > 0; o >>= 1) v += __shfl_xor(v, o, 64);
  __syncthreads();
  if ((threadIdx.x & 63) == 0) buf[threadIdx.x >> 6] = v;
  __syncthreads();
  return buf[0] + buf[1] + buf[2] + buf[3];
}
__device__ __forceinline__ float gelu_tanh(float x) {
  float x3 = x * x * x;
  return 0.5f * x * (1.0f + tanhf(0.7978845608028654f * (x + 0.044715f * x3)));
}

// ---------------- tiny prep kernels ----------------
__global__ void em_kernel(const float* __restrict__ e, const float* __restrict__ mod,
                          float* __restrict__ em) {
  int g = blockIdx.x * 256 + threadIdx.x;
  if (g < 6 * DIMC) em[g] = e[g] + mod[g];
}

__global__ void cs_kernel(const float* __restrict__ af, const float* __restrict__ ah,
                          const float* __restrict__ aw, float* __restrict__ cs) {
  int g = blockIdx.x * 256 + threadIdx.x;   // 2560*64
  if (g >= SEQL * 64) return;
  int s = g >> 6, i = g & 63;
  int fi = s / 640, rem = s % 640, hi = rem >> 5, wi = rem & 31;
  float ang;
  if (i < 22)       ang = af[fi * 22 + i];          // cf = 22
  else if (i < 43)  ang = ah[hi * 21 + (i - 22)];   // ch = 21
  else              ang = aw[wi * 21 + (i - 43)];   // cw = 21
  cs[2 * g]     = cosf(ang);
  cs[2 * g + 1] = sinf(ang);
}

// float -> bf16 cast (ctx)
__global__ void castbf_kernel(const float* __restrict__ in, ushort* __restrict__ out, int n4) {
  int g = (blockIdx.x * 256 + threadIdx.x);
  if (g >= n4) return;
  float4 v = *(const float4*)&in[g * 4];
  uint2 p;
  p.x = (uint)f2bf(v.x) | ((uint)f2bf(v.y) << 16);
  p.y = (uint)f2bf(v.z) | ((uint)f2bf(v.w) << 16);
  *(uint2*)&out[g * 4] = p;
}

// ---------------- LayerNorm (fp32 in -> bf16 out): y = LN(x)*(avec[+1])+bvec ----------------
__global__ __launch_bounds__(256) void ln_bf_kernel(const float* __restrict__ x,
    ushort* __restrict__ y, const float* __restrict__ avec,
    const float* __restrict__ bvec, int addone) {
  __shared__ float buf[4];
  const int row = blockIdx.x, tid = threadIdx.x;
  const float* xr = x + (size_t)row * DIMC;
  float4 v0 = *(const float4*)&xr[4 * tid];
  float4 v1 = *(const float4*)&xr[1024 + 4 * tid];
  float s = v0.x + v0.y + v0.z + v0.w + v1.x + v1.y + v1.z + v1.w;
  s = block_reduce_sum(s, buf);
  float mean = s * (1.0f / 2048.0f);
  float d0[4] = {v0.x - mean, v0.y - mean, v0.z - mean, v0.w - mean};
  float d1[4] = {v1.x - mean, v1.y - mean, v1.z - mean, v1.w - mean};
  float ss = d0[0]*d0[0]+d0[1]*d0[1]+d0[2]*d0[2]+d0[3]*d0[3]
           + d1[0]*d1[0]+d1[1]*d1[1]+d1[2]*d1[2]+d1[3]*d1[3];
  ss = block_reduce_sum(ss, buf);
  float rstd = rsqrtf(ss * (1.0f / 2048.0f) + LN_EPS);
  float add = addone ? 1.0f : 0.0f;
  float4 a0 = *(const float4*)&avec[4 * tid];
  float4 a1 = *(const float4*)&avec[1024 + 4 * tid];
  float4 b0 = *(const float4*)&bvec[4 * tid];
  float4 b1 = *(const float4*)&bvec[1024 + 4 * tid];
  float o0[4], o1[4];
  o0[0] = d0[0]*rstd*(a0.x+add)+b0.x; o0[1] = d0[1]*rstd*(a0.y+add)+b0.y;
  o0[2] = d0[2]*rstd*(a0.z+add)+b0.z; o0[3] = d0[3]*rstd*(a0.w+add)+b0.w;
  o1[0] = d1[0]*rstd*(a1.x+add)+b1.x; o1[1] = d1[1]*rstd*(a1.y+add)+b1.y;
  o1[2] = d1[2]*rstd*(a1.z+add)+b1.z; o1[3] = d1[3]*rstd*(a1.w+add)+b1.w;
  ushort* yr = y + (size_t)row * DIMC;
  uint2 p0, p1;
  p0.x = (uint)f2bf(o0[0]) | ((uint)f2bf(o0[1]) << 16);
  p0.y = (uint)f2bf(o0[2]) | ((uint)f2bf(o0[3]) << 16);
  p1.x = (uint)f2bf(o1[0]) | ((uint)f2bf(o1[1]) << 16);
  p1.y = (uint)f2bf(o1[2]) | ((uint)f2bf(o1[3]) << 16);
  *(uint2*)&yr[4 * tid] = p0;
  *(uint2*)&yr[1024 + 4 * tid] = p1;
}

// ---------------- RMSNorm (bf16 in-place) + optional RoPE ----------------
__global__ __launch_bounds__(256) void rms_rope_bf(ushort* __restrict__ q,
    const float* __restrict__ wv, const float* __restrict__ cs, int do_rope) {
  __shared__ float buf[4];
  const int row = blockIdx.x, tid = threadIdx.x;
  ushort* xr = q + (size_t)row * DIMC + tid * 8;
  uint4 raw = *(const uint4*)xr;
  float v[8];
  v[0] = bf2f((ushort)(raw.x & 0xFFFF)); v[1] = bf2f((ushort)(raw.x >> 16));
  v[2] = bf2f((ushort)(raw.y & 0xFFFF)); v[3] = bf2f((ushort)(raw.y >> 16));
  v[4] = bf2f((ushort)(raw.z & 0xFFFF)); v[5] = bf2f((ushort)(raw.z >> 16));
  v[6] = bf2f((ushort)(raw.w & 0xFFFF)); v[7] = bf2f((ushort)(raw.w >> 16));
  float ss = 0.0f;
  #pragma unroll
  for (int i = 0; i < 8; ++i) ss += v[i] * v[i];
  ss = block_reduce_sum(ss, buf);
  float rr = rsqrtf(ss * (1.0f / 2048.0f) + LN_EPS);
  float4 w0 = *(const float4*)&wv[tid * 8];
  float4 w1 = *(const float4*)&wv[tid * 8 + 4];
  v[0] *= rr * w0.x; v[1] *= rr * w0.y; v[2] *= rr * w0.z; v[3] *= rr * w0.w;
  v[4] *= rr * w1.x; v[5] *= rr * w1.y; v[6] *= rr * w1.z; v[7] *= rr * w1.w;
  if (do_rope) {
    int p0 = (4 * tid) & 63;   // 4 pairs, never crossing the 64-pair head block
    const float2* ct = (const float2*)cs + (size_t)row * 64 + p0;
    #pragma unroll
    for (int i = 0; i < 4; ++i) {
      float2 c = ct[i];
      float e = v[2 * i], o = v[2 * i + 1];
      v[2 * i]     = e * c.x - o * c.y;
      v[2 * i + 1] = e * c.y + o * c.x;
    }
  }
  uint4 out;
  out.x = (uint)f2bf(v[0]) | ((uint)f2bf(v[1]) << 16);
  out.y = (uint)f2bf(v[2]) | ((uint)f2bf(v[3]) << 16);
  out.z = (uint)f2bf(v[4]) | ((uint)f2bf(v[5]) << 16);
  out.w = (uint)f2bf(v[6]) | ((uint)f2bf(v[7]) << 16);
  *(uint4*)xr = out;
}

// ---------------- bf16 MFMA GEMM: C = epilogue(A[MxK](bf16) @ W[KxN](fp32)) ----------------
// MODE 0: C(bf16) = acc + bias
// MODE 1: C(bf16) = gelu(acc + bias)
// MODE 2: C(f32)  = res + (acc + bias) * evec
// MODE 3: C(f32)  = res + (acc + bias)
// 128x128 tile, BK=32, 4 waves (2x2), each wave 64x64 via 4x4 x mfma_16x16x32_bf16.
template<int MODE>
__global__ __launch_bounds__(256) void mgemm_kernel(
    const ushort* __restrict__ A, const float* __restrict__ W,
    const float* __restrict__ bias, const float* __restrict__ res,
    const float* __restrict__ evec, void* __restrict__ Cout,
    int K, int ldn) {
  __shared__ __align__(16) ushort As[128 * 40];   // [m][k], stride 40 (80B, 16B-mult)
  __shared__ __align__(16) ushort Bs[128 * 44];   // [n][k], stride 44 (88B, 8B-mult, 16 banks)
  const int tid = threadIdx.x;
  const int lane = tid & 63, wv = tid >> 6;
  const int wm = (wv >> 1) * 64, wn = (wv & 1) * 64;
  const int m0 = blockIdx.y * 128, n0 = blockIdx.x * 128;

  fx4 acc[4][4];
  #pragma unroll
  for (int i = 0; i < 4; ++i)
    #pragma unroll
    for (int j = 0; j < 4; ++j) acc[i][j] = (fx4){0.f, 0.f, 0.f, 0.f};

  const int ar = tid >> 1, ah = (tid & 1) * 16;     // A: row, k-half
  const int bn = tid & 127, bkg = (tid >> 7) * 4;   // B: n col, k-group base

  const int lr = lane & 15, lk = (lane >> 4) * 8;   // frag row/col & k-offset

  for (int k0 = 0; k0 < K; k0 += 32) {
    __syncthreads();
    {  // A tile: 128 x 32 bf16, contiguous copy
      const ushort* ga = A + (size_t)(m0 + ar) * K + k0 + ah;
      uint4 v0 = *(const uint4*)ga;
      uint4 v1 = *(const uint4*)(ga + 8);
      *(uint4*)&As[ar * 40 + ah]     = v0;
      *(uint4*)&As[ar * 40 + ah + 8] = v1;
    }
    // B tile: 32 x 128 fp32 -> transpose -> Bs[n][k] bf16
    #pragma unroll
    for (int p = 0; p < 4; ++p) {
      int kk = bkg + p * 8;
      float w0 = W[(size_t)(k0 + kk    ) * ldn + n0 + bn];
      float w1 = W[(size_t)(k0 + kk + 1) * ldn + n0 + bn];
      float w2 = W[(size_t)(k0 + kk + 2) * ldn + n0 + bn];
      float w3 = W[(size_t)(k0 + kk + 3) * ldn + n0 + bn];
      uint2 pk;
      pk.x = (uint)f2bf(w0) | ((uint)f2bf(w1) << 16);
      pk.y = (uint)f2bf(w2) | ((uint)f2bf(w3) << 16);
      *(uint2*)&Bs[bn * 44 + kk] = pk;
    }
    __syncthreads();

    bfx8 af[4];
    #pragma unroll
    for (int mi = 0; mi < 4; ++mi)
      af[mi] = *(const bfx8*)&As[(wm + mi * 16 + lr) * 40 + lk];
    bfx8 bfr[4];
    #pragma unroll
    for (int ni = 0; ni < 4; ++ni) {
      const ushort* bp = &Bs[(wn + ni * 16 + lr) * 44 + lk];
      bfx4 lo = *(const bfx4*)bp;
      bfx4 hi = *(const bfx4*)(bp + 4);
      bfx8 b;
      b[0] = lo[0]; b[1] = lo[1]; b[2] = lo[2]; b[3] = lo[3];
      b[4] = hi[0]; b[5] = hi[1]; b[6] = hi[2]; b[7] = hi[3];
      bfr[ni] = b;
    }
    #pragma unroll
    for (int mi = 0; mi < 4; ++mi)
      #pragma unroll
      for (int ni = 0; ni < 4; ++ni)
        acc[mi][ni] = __builtin_amdgcn_mfma_f32_16x16x32_bf16(af[mi], bfr[ni], acc[mi][ni], 0, 0, 0);
  }

  // epilogue: D[row=(lane>>4)*4+r][col=lane&15] per frag
  const int r4 = (lane >> 4) * 4;
  #pragma unroll
  for (int ni = 0; ni < 4; ++ni) {
    const int col = n0 + wn + ni * 16 + lr;
    const float bv = bias[col];
    float ev = 0.0f;
    if constexpr (MODE == 2) ev = evec[col];
    #pragma unroll
    for (int mi = 0; mi < 4; ++mi) {
      #pragma unroll
      for (int r = 0; r < 4; ++r) {
        const int row = m0 + wm + mi * 16 + r4 + r;
        const size_t off = (size_t)row * ldn + col;
        float v = acc[mi][ni][r] + bv;
        if constexpr (MODE == 1) v = gelu_tanh(v);
        if constexpr (MODE == 2) v = res[off] + v * ev;
        if constexpr (MODE == 3) v = res[off] + v;
        if constexpr (MODE <= 1) ((ushort*)Cout)[off] = f2bf(v);
        else                     ((float*)Cout)[off]  = v;
      }
    }
  }
}

// ---------------- flash attention, bf16 in / bf16 out, fp32 math ----------------
__global__ __launch_bounds__(256) void attn_bf_kernel(
    const ushort* __restrict__ Q, const ushort* __restrict__ K,
    const ushort* __restrict__ V, ushort* __restrict__ O, int Skv) {
  __shared__ float Qs[64][132];
  __shared__ float Ks[128][33];
  __shared__ float Ss[64][33];
  __shared__ float mS[64], lS[64], aS[64];

  const int tid = threadIdx.x;
  const int ty = tid >> 4, tx = tid & 15;
  const int q0 = blockIdx.x * 64;
  const int cb = blockIdx.y * HD;

  #pragma unroll
  for (int p = 0; p < 4; ++p) {
    int idx = tid + p * 256;          // 0..1023
    int r = idx >> 4, f = idx & 15;   // row 0..63, col-block 0..15
    uint4 raw = *(const uint4*)&Q[(size_t)(q0 + r) * DIMC + cb + 8 * f];
    float* qp = &Qs[r][8 * f];
    qp[0] = bf2f((ushort)(raw.x & 0xFFFF)) * ATTN_SCALE;
    qp[1] = bf2f((ushort)(raw.x >> 16))    * ATTN_SCALE;
    qp[2] = bf2f((ushort)(raw.y & 0xFFFF)) * ATTN_SCALE;
    qp[3] = bf2f((ushort)(raw.y >> 16))    * ATTN_SCALE;
    qp[4] = bf2f((ushort)(raw.z & 0xFFFF)) * ATTN_SCALE;
    qp[5] = bf2f((ushort)(raw.z >> 16))    * ATTN_SCALE;
    qp[6] = bf2f((ushort)(raw.w & 0xFFFF)) * ATTN_SCALE;
    qp[7] = bf2f((ushort)(raw.w >> 16))    * ATTN_SCALE;
  }
  if (tid < 64) { mS[tid] = -3.0e38f; lS[tid] = 0.0f; }

  float oacc[4][8];
  #pragma unroll
  for (int i = 0; i < 4; ++i)
    #pragma unroll
    for (int c = 0; c < 8; ++c) oacc[i][c] = 0.0f;

  for (int kv0 = 0; kv0 < Skv; kv0 += 32) {
    __syncthreads();
    #pragma unroll
    for (int p = 0; p < 2; ++p) {
      int idx = tid + p * 256;         // 0..511
      int r = idx >> 4, f = idx & 15;  // row 0..31, col-block 0..15
      uint4 raw = *(const uint4*)&K[(size_t)(kv0 + r) * DIMC + cb + 8 * f];
      Ks[8 * f + 0][r] = bf2f((ushort)(raw.x & 0xFFFF));
      Ks[8 * f + 1][r] = bf2f((ushort)(raw.x >> 16));
      Ks[8 * f + 2][r] = bf2f((ushort)(raw.y & 0xFFFF));
      Ks[8 * f + 3][r] = bf2f((ushort)(raw.y >> 16));
      Ks[8 * f + 4][r] = bf2f((ushort)(raw.z & 0xFFFF));
      Ks[8 * f + 5][r] = bf2f((ushort)(raw.z >> 16));
      Ks[8 * f + 6][r] = bf2f((ushort)(raw.w & 0xFFFF));
      Ks[8 * f + 7][r] = bf2f((ushort)(raw.w >> 16));
    }
    __syncthreads();

    float sacc[4][2];
    #pragma unroll
    for (int i = 0; i < 4; ++i) { sacc[i][0] = 0.f; sacc[i][1] = 0.f; }
    #pragma unroll 2
    for (int k4 = 0; k4 < 128; k4 += 4) {
      float qa[4][4];
      #pragma unroll
      for (int i = 0; i < 4; ++i) {
        float4 t = *(const float4*)&Qs[ty * 4 + i][k4];
        qa[i][0] = t.x; qa[i][1] = t.y; qa[i][2] = t.z; qa[i][3] = t.w;
      }
      #pragma unroll
      for (int u = 0; u < 4; ++u) {
        float kv0v = Ks[k4 + u][tx * 2];
        float kv1v = Ks[k4 + u][tx * 2 + 1];
        #pragma unroll
        for (int i = 0; i < 4; ++i) {
          sacc[i][0] = fmaf(qa[i][u], kv0v, sacc[i][0]);
          sacc[i][1] = fmaf(qa[i][u], kv1v, sacc[i][1]);
        }
      }
    }
    #pragma unroll
    for (int i = 0; i < 4; ++i) {
      Ss[ty * 4 + i][tx * 2]     = sacc[i][0];
      Ss[ty * 4 + i][tx * 2 + 1] = sacc[i][1];
    }
    __syncthreads();

    if (tid < 64) {
      float mo = mS[tid];
      float pm = mo;
      #pragma unroll 4
      for (int j = 0; j < 32; ++j) pm = fmaxf(pm, Ss[tid][j]);
      float alpha = __expf(mo - pm);
      float sum = 0.0f;
      #pragma unroll 4
      for (int j = 0; j < 32; ++j) {
        float p = __expf(Ss[tid][j] - pm);
        Ss[tid][j] = p;
        sum += p;
      }
      lS[tid] = lS[tid] * alpha + sum;
      mS[tid] = pm;
      aS[tid] = alpha;
    }
    __syncthreads();

    float al[4];
    #pragma unroll
    for (int i = 0; i < 4; ++i) al[i] = aS[ty * 4 + i];
    #pragma unroll
    for (int i = 0; i < 4; ++i)
      #pragma unroll
      for (int c = 0; c < 8; ++c) oacc[i][c] *= al[i];
    #pragma unroll 4
    for (int j = 0; j < 32; ++j) {
      uint4 raw = *(const uint4*)&V[(size_t)(kv0 + j) * DIMC + cb + tx * 8];
      float vv[8];
      vv[0] = bf2f((ushort)(raw.x & 0xFFFF)); vv[1] = bf2f((ushort)(raw.x >> 16));
      vv[2] = bf2f((ushort)(raw.y & 0xFFFF)); vv[3] = bf2f((ushort)(raw.y >> 16));
      vv[4] = bf2f((ushort)(raw.z & 0xFFFF)); vv[5] = bf2f((ushort)(raw.z >> 16));
      vv[6] = bf2f((ushort)(raw.w & 0xFFFF)); vv[7] = bf2f((ushort)(raw.w >> 16));
      float pv[4] = {Ss[ty * 4 + 0][j], Ss[ty * 4 + 1][j],
                     Ss[ty * 4 + 2][j], Ss[ty * 4 + 3][j]};
      #pragma unroll
      for (int i = 0; i < 4; ++i)
        #pragma unroll
        for (int c = 0; c < 8; ++c)
          oacc[i][c] = fmaf(pv[i], vv[c], oacc[i][c]);
    }
  }

  #pragma unroll
  for (int i = 0; i < 4; ++i) {
    float inv = 1.0f / lS[ty * 4 + i];
    uint4 o;
    o.x = (uint)f2bf(oacc[i][0] * inv) | ((uint)f2bf(oacc[i][1] * inv) << 16);
    o.y = (uint)f2bf(oacc[i][2] * inv) | ((uint)f2bf(oacc[i][3] * inv) << 16);
    o.z = (uint)f2bf(oacc[i][4] * inv) | ((uint)f2bf(oacc[i][5] * inv) << 16);
    o.w = (uint)f2bf(oacc[i][6] * inv) | ((uint)f2bf(oacc[i][7] * inv) << 16);
    *(uint4*)&O[(size_t)(q0 + ty * 4 + i) * DIMC + cb + tx * 8] = o;
  }
}

// ---------------- host side ----------------
static inline void mgemm_launch(int mode, const ushort* A, const float* W,
    const float* bias, const float* res, const float* evec, void* C,
    int M, int N, int K, hipStream_t s) {
  dim3 grid(N / 128, M / 128), blk(256);
  switch (mode) {
    case 0: mgemm_kernel<0><<<grid, blk, 0, s>>>(A, W, bias, res, evec, C, K, N); break;
    case 1: mgemm_kernel<1><<<grid, blk, 0, s>>>(A, W, bias, res, evec, C, K, N); break;
    case 2: mgemm_kernel<2><<<grid, blk, 0, s>>>(A, W, bias, res, evec, C, K, N); break;
    case 3: mgemm_kernel<3><<<grid, blk, 0, s>>>(A, W, bias, res, evec, C, K, N); break;
  }
}

extern "C" void kernel_launch(void* const* d_in, const int* in_sizes, int n_in,
                              void* d_out, int out_size, void* d_ws, size_t ws_size,
                              hipStream_t stream) {
  const float* x     = (const float*)d_in[0];
  const float* e     = (const float*)d_in[1];
  const float* ctx   = (const float*)d_in[2];
  const float* q_w   = (const float*)d_in[6];
  const float* q_b   = (const float*)d_in[7];
  const float* k_w   = (const float*)d_in[8];
  const float* k_b   = (const float*)d_in[9];
  const float* v_w   = (const float*)d_in[10];
  const float* v_b   = (const float*)d_in[11];
  const float* o_w   = (const float*)d_in[12];
  const float* o_b   = (const float*)d_in[13];
  const float* nq_w  = (const float*)d_in[14];
  const float* nk_w  = (const float*)d_in[15];
  const float* cq_w  = (const float*)d_in[16];
  const float* cq_b  = (const float*)d_in[17];
  const float* ck_w  = (const float*)d_in[18];
  const float* ck_b  = (const float*)d_in[19];
  const float* cv_w  = (const float*)d_in[20];
  const float* cv_b  = (const float*)d_in[21];
  const float* co_w  = (const float*)d_in[22];
  const float* co_b  = (const float*)d_in[23];
  const float* cnq_w = (const float*)d_in[24];
  const float* cnk_w = (const float*)d_in[25];
  const float* n3g   = (const float*)d_in[26];
  const float* n3b   = (const float*)d_in[27];
  const float* w1    = (const float*)d_in[28];
  const float* b1    = (const float*)d_in[29];
  const float* w2    = (const float*)d_in[30];
  const float* b2    = (const float*)d_in[31];
  const float* mod   = (const float*)d_in[32];
  const float* ang_f = (const float*)d_in[33];
  const float* ang_h = (const float*)d_in[34];
  const float* ang_w = (const float*)d_in[35];
  float* out = (float*)d_out;

  // ---- workspace layout (bytes), ~79 MB ----
  const size_t SB  = (size_t)SEQL * DIMC;   // 5,242,880 elems
  char* w = (char*)d_ws;
  float*  em    = (float*)w;   w += 6 * DIMC * 4;
  float*  cs    = (float*)w;   w += (size_t)SEQL * 128 * 4;
  ushort* actbf = (ushort*)w;  w += SB * 2;                 // y / cx / y3
  ushort* Qbf   = (ushort*)w;  w += SB * 2;                 // q / cq   (hidden part 1)
  ushort* Kbf   = (ushort*)w;  w += SB * 2;                 // k / ck   (hidden part 2)
  ushort* Vbf   = (ushort*)w;  w += SB * 2;                 // v / cv   (hidden part 3)
  ushort* abf   = (ushort*)w;  w += SB * 2;                 // attn out (hidden part 4)
  float*  x2f   = (float*)w;   w += SB * 4;                 // x2, then x3 (in place)
  ushort* ctxbf = (ushort*)w;  w += (size_t)CTXL * CTXD * 2;
  ushort* hidden = Qbf;        // 2560*8192 bf16 = exactly Qbf..abf end
  const size_t need = (size_t)(w - (char*)d_ws);
  if (ws_size < need) return;

  const float* e0 = em + 0 * DIMC;
  const float* e1 = em + 1 * DIMC;
  const float* e2 = em + 2 * DIMC;
  const float* e3 = em + 3 * DIMC;
  const float* e4 = em + 4 * DIMC;
  const float* e5 = em + 5 * DIMC;

  em_kernel<<<48, 256, 0, stream>>>(e, mod, em);
  cs_kernel<<<640, 256, 0, stream>>>(ang_f, ang_h, ang_w, cs);
  castbf_kernel<<<2048, 256, 0, stream>>>(ctx, ctxbf, (CTXL * CTXD) / 4);

  // y = LN(x)*(1+e1)+e0 -> bf16
  ln_bf_kernel<<<SEQL, 256, 0, stream>>>(x, actbf, e1, e0, 1);

  // QKV projections (bf16 out)
  mgemm_launch(0, actbf, q_w, q_b, nullptr, nullptr, Qbf, SEQL, DIMC, DIMC, stream);
  mgemm_launch(0, actbf, k_w, k_b, nullptr, nullptr, Kbf, SEQL, DIMC, DIMC, stream);
  mgemm_launch(0, actbf, v_w, v_b, nullptr, nullptr, Vbf, SEQL, DIMC, DIMC, stream);

  // rmsnorm + rope on q,k (bf16 in-place)
  rms_rope_bf<<<SEQL, 256, 0, stream>>>(Qbf, nq_w, cs, 1);
  rms_rope_bf<<<SEQL, 256, 0, stream>>>(Kbf, nk_w, cs, 1);

  // self attention -> abf
  attn_bf_kernel<<<dim3(SEQL / 64, NHEADS), 256, 0, stream>>>(Qbf, Kbf, Vbf, abf, SEQL);

  // x2 = x + (a @ o_w + o_b) * e2 -> f32
  mgemm_launch(2, abf, o_w, o_b, x, e2, x2f, SEQL, DIMC, DIMC, stream);

  // cx = LN(x2, g, b) -> bf16
  ln_bf_kernel<<<SEQL, 256, 0, stream>>>(x2f, actbf, n3g, n3b, 0);

  // cq (bf16) + rms
  mgemm_launch(0, actbf, cq_w, cq_b, nullptr, nullptr, Qbf, SEQL, DIMC, DIMC, stream);
  rms_rope_bf<<<SEQL, 256, 0, stream>>>(Qbf, cnq_w, cs, 0);

  // ck, cv from context (K = 4096)
  mgemm_launch(0, ctxbf, ck_w, ck_b, nullptr, nullptr, Kbf, CTXL, DIMC, CTXD, stream);
  rms_rope_bf<<<CTXL, 256, 0, stream>>>(Kbf, cnk_w, cs, 0);
  mgemm_launch(0, ctxbf, cv_w, cv_b, nullptr, nullptr, Vbf, CTXL, DIMC, CTXD, stream);

  // cross attention -> abf
  attn_bf_kernel<<<dim3(SEQL / 64, NHEADS), 256, 0, stream>>>(Qbf, Kbf, Vbf, abf, CTXL);

  // x3 = x2 + (ca @ co_w + co_b) -> x2f in place (same-offset read/write per thread)
  mgemm_launch(3, abf, co_w, co_b, x2f, nullptr, x2f, SEQL, DIMC, DIMC, stream);

  // y3 = LN(x3)*(1+e4)+e3 -> bf16
  ln_bf_kernel<<<SEQL, 256, 0, stream>>>(x2f, actbf, e4, e3, 1);

  // FFN: hidden = gelu(y3 @ w1 + b1) (bf16, N=8192), out = x3 + (hidden @ w2 + b2)*e5
  mgemm_launch(1, actbf, w1, b1, nullptr, nullptr, hidden, SEQL, FFND, DIMC, stream);
  mgemm_launch(2, hidden, w2, b2, x2f, e5, out, SEQL, DIMC, FFND, stream);
}

// Round 5
// 2069.267 us; speedup vs baseline: 3.6361x; 1.6851x over previous
//
#include <hip/hip_runtime.h>
#include <cstdint>

// ---------------- problem constants ----------------
#define SEQL     2560     // 4*20*32
#define DIMC     2048
#define NHEADS   16
#define HD       128
#define FFND     8192
#define CTXD     4096
#define CTXL     512
#define LN_EPS   1e-6f
#define ATTN_SCALE 0.08838834764831845f  // 128^-0.5

typedef __attribute__((ext_vector_type(8))) short bfx8;   // MFMA A/B frag (8 bf16)
typedef __attribute__((ext_vector_type(4))) short bfx4;
typedef __attribute__((ext_vector_type(4))) float fx4;    // MFMA C/D frag

// ---------------- helpers ----------------
__device__ __forceinline__ float bf2f(ushort h) {
  union { uint u; float f; } c; c.u = ((uint)h) << 16; return c.f;
}
__device__ __forceinline__ ushort f2bf(float f) {
  union { float f; uint u; } c; c.f = f;
  uint u = c.u;
  return (ushort)((u + 0x7FFFu + ((u >> 16) & 1u)) >> 16);   // RNE
}
__device__ __forceinline__ float block_reduce_sum(float v, float* buf) {
  #pragma unroll
  for (int o = 32; o > 0; o >>= 1) v += __shfl_xor(v, o, 64);
  __syncthreads();
  if ((threadIdx.x & 63) == 0) buf[threadIdx.x >> 6] = v;
  __syncthreads();
  return buf[0] + buf[1] + buf[2] + buf[3];
}
__device__ __forceinline__ float gelu_tanh(float x) {
  float x3 = x * x * x;
  return 0.5f * x * (1.0f + tanhf(0.7978845608028654f * (x + 0.044715f * x3)));
}

// ---------------- tiny prep kernels ----------------
__global__ void em_kernel(const float* __restrict__ e, const float* __restrict__ mod,
                          float* __restrict__ em) {
  int g = blockIdx.x * 256 + threadIdx.x;
  if (g < 6 * DIMC) em[g] = e[g] + mod[g];
}

__global__ void cs_kernel(const float* __restrict__ af, const float* __restrict__ ah,
                          const float* __restrict__ aw, float* __restrict__ cs) {
  int g = blockIdx.x * 256 + threadIdx.x;   // 2560*64
  if (g >= SEQL * 64) return;
  int s = g >> 6, i = g & 63;
  int fi = s / 640, rem = s % 640, hi = rem >> 5, wi = rem & 31;
  float ang;
  if (i < 22)       ang = af[fi * 22 + i];          // cf = 22
  else if (i < 43)  ang = ah[hi * 21 + (i - 22)];   // ch = 21
  else              ang = aw[wi * 21 + (i - 43)];   // cw = 21
  cs[2 * g]     = cosf(ang);
  cs[2 * g + 1] = sinf(ang);
}

// float -> bf16 cast (ctx)
__global__ void castbf_kernel(const float* __restrict__ in, ushort* __restrict__ out, int n4) {
  int g = (blockIdx.x * 256 + threadIdx.x);
  if (g >= n4) return;
  float4 v = *(const float4*)&in[g * 4];
  uint2 p;
  p.x = (uint)f2bf(v.x) | ((uint)f2bf(v.y) << 16);
  p.y = (uint)f2bf(v.z) | ((uint)f2bf(v.w) << 16);
  *(uint2*)&out[g * 4] = p;
}

// ---------------- LayerNorm (fp32 in -> bf16 out): y = LN(x)*(avec[+1])+bvec ----------------
__global__ __launch_bounds__(256) void ln_bf_kernel(const float* __restrict__ x,
    ushort* __restrict__ y, const float* __restrict__ avec,
    const float* __restrict__ bvec, int addone) {
  __shared__ float buf[4];
  const int row = blockIdx.x, tid = threadIdx.x;
  const float* xr = x + (size_t)row * DIMC;
  float4 v0 = *(const float4*)&xr[4 * tid];
  float4 v1 = *(const float4*)&xr[1024 + 4 * tid];
  float s = v0.x + v0.y + v0.z + v0.w + v1.x + v1.y + v1.z + v1.w;
  s = block_reduce_sum(s, buf);
  float mean = s * (1.0f / 2048.0f);
  float d0[4] = {v0.x - mean, v0.y - mean, v0.z - mean, v0.w - mean};
  float d1[4] = {v1.x - mean, v1.y - mean, v1.z - mean, v1.w - mean};
  float ss = d0[0]*d0[0]+d0[1]*d0[1]+d0[2]*d0[2]+d0[3]*d0[3]
           + d1[0]*d1[0]+d1[1]*d1[1]+d1[2]*d1[2]+d1[3]*d1[3];
  ss = block_reduce_sum(ss, buf);
  float rstd = rsqrtf(ss * (1.0f / 2048.0f) + LN_EPS);
  float add = addone ? 1.0f : 0.0f;
  float4 a0 = *(const float4*)&avec[4 * tid];
  float4 a1 = *(const float4*)&avec[1024 + 4 * tid];
  float4 b0 = *(const float4*)&bvec[4 * tid];
  float4 b1 = *(const float4*)&bvec[1024 + 4 * tid];
  float o0[4], o1[4];
  o0[0] = d0[0]*rstd*(a0.x+add)+b0.x; o0[1] = d0[1]*rstd*(a0.y+add)+b0.y;
  o0[2] = d0[2]*rstd*(a0.z+add)+b0.z; o0[3] = d0[3]*rstd*(a0.w+add)+b0.w;
  o1[0] = d1[0]*rstd*(a1.x+add)+b1.x; o1[1] = d1[1]*rstd*(a1.y+add)+b1.y;
  o1[2] = d1[2]*rstd*(a1.z+add)+b1.z; o1[3] = d1[3]*rstd*(a1.w+add)+b1.w;
  ushort* yr = y + (size_t)row * DIMC;
  uint2 p0, p1;
  p0.x = (uint)f2bf(o0[0]) | ((uint)f2bf(o0[1]) << 16);
  p0.y = (uint)f2bf(o0[2]) | ((uint)f2bf(o0[3]) << 16);
  p1.x = (uint)f2bf(o1[0]) | ((uint)f2bf(o1[1]) << 16);
  p1.y = (uint)f2bf(o1[2]) | ((uint)f2bf(o1[3]) << 16);
  *(uint2*)&yr[4 * tid] = p0;
  *(uint2*)&yr[1024 + 4 * tid] = p1;
}

// ---------------- RMSNorm (bf16 in-place) + optional RoPE ----------------
__global__ __launch_bounds__(256) void rms_rope_bf(ushort* __restrict__ q,
    const float* __restrict__ wv, const float* __restrict__ cs, int do_rope) {
  __shared__ float buf[4];
  const int row = blockIdx.x, tid = threadIdx.x;
  ushort* xr = q + (size_t)row * DIMC + tid * 8;
  uint4 raw = *(const uint4*)xr;
  float v[8];
  v[0] = bf2f((ushort)(raw.x & 0xFFFF)); v[1] = bf2f((ushort)(raw.x >> 16));
  v[2] = bf2f((ushort)(raw.y & 0xFFFF)); v[3] = bf2f((ushort)(raw.y >> 16));
  v[4] = bf2f((ushort)(raw.z & 0xFFFF)); v[5] = bf2f((ushort)(raw.z >> 16));
  v[6] = bf2f((ushort)(raw.w & 0xFFFF)); v[7] = bf2f((ushort)(raw.w >> 16));
  float ss = 0.0f;
  #pragma unroll
  for (int i = 0; i < 8; ++i) ss += v[i] * v[i];
  ss = block_reduce_sum(ss, buf);
  float rr = rsqrtf(ss * (1.0f / 2048.0f) + LN_EPS);
  float4 w0 = *(const float4*)&wv[tid * 8];
  float4 w1 = *(const float4*)&wv[tid * 8 + 4];
  v[0] *= rr * w0.x; v[1] *= rr * w0.y; v[2] *= rr * w0.z; v[3] *= rr * w0.w;
  v[4] *= rr * w1.x; v[5] *= rr * w1.y; v[6] *= rr * w1.z; v[7] *= rr * w1.w;
  if (do_rope) {
    int p0 = (4 * tid) & 63;
    const float2* ct = (const float2*)cs + (size_t)row * 64 + p0;
    #pragma unroll
    for (int i = 0; i < 4; ++i) {
      float2 c = ct[i];
      float e = v[2 * i], o = v[2 * i + 1];
      v[2 * i]     = e * c.x - o * c.y;
      v[2 * i + 1] = e * c.y + o * c.x;
    }
  }
  uint4 out;
  out.x = (uint)f2bf(v[0]) | ((uint)f2bf(v[1]) << 16);
  out.y = (uint)f2bf(v[2]) | ((uint)f2bf(v[3]) << 16);
  out.z = (uint)f2bf(v[4]) | ((uint)f2bf(v[5]) << 16);
  out.w = (uint)f2bf(v[6]) | ((uint)f2bf(v[7]) << 16);
  *(uint4*)xr = out;
}

// ---------------- bf16 MFMA GEMM (unchanged from round 4) ----------------
template<int MODE>
__global__ __launch_bounds__(256) void mgemm_kernel(
    const ushort* __restrict__ A, const float* __restrict__ W,
    const float* __restrict__ bias, const float* __restrict__ res,
    const float* __restrict__ evec, void* __restrict__ Cout,
    int K, int ldn) {
  __shared__ __align__(16) ushort As[128 * 40];
  __shared__ __align__(16) ushort Bs[128 * 44];
  const int tid = threadIdx.x;
  const int lane = tid & 63, wv = tid >> 6;
  const int wm = (wv >> 1) * 64, wn = (wv & 1) * 64;
  const int m0 = blockIdx.y * 128, n0 = blockIdx.x * 128;

  fx4 acc[4][4];
  #pragma unroll
  for (int i = 0; i < 4; ++i)
    #pragma unroll
    for (int j = 0; j < 4; ++j) acc[i][j] = (fx4){0.f, 0.f, 0.f, 0.f};

  const int ar = tid >> 1, ah = (tid & 1) * 16;
  const int bn = tid & 127, bkg = (tid >> 7) * 4;
  const int lr = lane & 15, lk = (lane >> 4) * 8;

  for (int k0 = 0; k0 < K; k0 += 32) {
    __syncthreads();
    {
      const ushort* ga = A + (size_t)(m0 + ar) * K + k0 + ah;
      uint4 v0 = *(const uint4*)ga;
      uint4 v1 = *(const uint4*)(ga + 8);
      *(uint4*)&As[ar * 40 + ah]     = v0;
      *(uint4*)&As[ar * 40 + ah + 8] = v1;
    }
    #pragma unroll
    for (int p = 0; p < 4; ++p) {
      int kk = bkg + p * 8;
      float w0 = W[(size_t)(k0 + kk    ) * ldn + n0 + bn];
      float w1 = W[(size_t)(k0 + kk + 1) * ldn + n0 + bn];
      float w2 = W[(size_t)(k0 + kk + 2) * ldn + n0 + bn];
      float w3 = W[(size_t)(k0 + kk + 3) * ldn + n0 + bn];
      uint2 pk;
      pk.x = (uint)f2bf(w0) | ((uint)f2bf(w1) << 16);
      pk.y = (uint)f2bf(w2) | ((uint)f2bf(w3) << 16);
      *(uint2*)&Bs[bn * 44 + kk] = pk;
    }
    __syncthreads();

    bfx8 af[4];
    #pragma unroll
    for (int mi = 0; mi < 4; ++mi)
      af[mi] = *(const bfx8*)&As[(wm + mi * 16 + lr) * 40 + lk];
    bfx8 bfr[4];
    #pragma unroll
    for (int ni = 0; ni < 4; ++ni) {
      const ushort* bp = &Bs[(wn + ni * 16 + lr) * 44 + lk];
      bfx4 lo = *(const bfx4*)bp;
      bfx4 hi = *(const bfx4*)(bp + 4);
      bfx8 b;
      b[0] = lo[0]; b[1] = lo[1]; b[2] = lo[2]; b[3] = lo[3];
      b[4] = hi[0]; b[5] = hi[1]; b[6] = hi[2]; b[7] = hi[3];
      bfr[ni] = b;
    }
    #pragma unroll
    for (int mi = 0; mi < 4; ++mi)
      #pragma unroll
      for (int ni = 0; ni < 4; ++ni)
        acc[mi][ni] = __builtin_amdgcn_mfma_f32_16x16x32_bf16(af[mi], bfr[ni], acc[mi][ni], 0, 0, 0);
  }

  const int r4 = (lane >> 4) * 4;
  #pragma unroll
  for (int ni = 0; ni < 4; ++ni) {
    const int col = n0 + wn + ni * 16 + lr;
    const float bv = bias[col];
    float ev = 0.0f;
    if constexpr (MODE == 2) ev = evec[col];
    #pragma unroll
    for (int mi = 0; mi < 4; ++mi) {
      #pragma unroll
      for (int r = 0; r < 4; ++r) {
        const int row = m0 + wm + mi * 16 + r4 + r;
        const size_t off = (size_t)row * ldn + col;
        float v = acc[mi][ni][r] + bv;
        if constexpr (MODE == 1) v = gelu_tanh(v);
        if constexpr (MODE == 2) v = res[off] + v * ev;
        if constexpr (MODE == 3) v = res[off] + v;
        if constexpr (MODE <= 1) ((ushort*)Cout)[off] = f2bf(v);
        else                     ((float*)Cout)[off]  = v;
      }
    }
  }
}

// ---------------- MFMA flash attention (bf16 in/out, fp32 accum) ----------------
// Per block: 1 head, 64 q rows, 4 waves. KV tiles of 64.
// QK^T: D[q][kpos] = mfma(A=Q rows, B=K rows).  PV: O^T[d][q] = mfma(A=Vt, B=P).
// All LDS tiles XOR-swizzled: ushort index ^= (row&7)<<3 (16B-granular).
#define SWZ(row, col, stride) ((((row) * (stride)) + (col)) ^ (((row) & 7) << 3))
__global__ __launch_bounds__(256) void attn_mfma_kernel(
    const ushort* __restrict__ Q, const ushort* __restrict__ K,
    const ushort* __restrict__ V, ushort* __restrict__ O, int Skv) {
  __shared__ __align__(16) ushort Qs[64 * 128];   // [q][d]   16384 B (reused as Os)
  __shared__ __align__(16) ushort Ks[64 * 128];   // [kpos][d] 16384 B
  __shared__ __align__(16) ushort Vt[128 * 64];   // [d][j]   16384 B
  __shared__ __align__(16) ushort Ps[64 * 64];    // [q][j]    8192 B
  __shared__ float aS[64];
  __shared__ float lS[64];

  const int tid = threadIdx.x;
  const int lane = tid & 63, w = tid >> 6;
  const int lr = lane & 15, lg = lane >> 4;
  const int q0 = blockIdx.x * 64;
  const int cb = blockIdx.y * HD;

  // stage Q (raw bf16 copy, swizzled)
  #pragma unroll
  for (int p = 0; p < 4; ++p) {
    int idx = tid + p * 256;          // 1024 chunks of 8 elems
    int r = idx >> 4, f = idx & 15;
    uint4 v = *(const uint4*)&Q[(size_t)(q0 + r) * DIMC + cb + f * 8];
    *(uint4*)&Qs[SWZ(r, f * 8, 128)] = v;
  }

  fx4 o[2][4];
  #pragma unroll
  for (int dt = 0; dt < 2; ++dt)
    #pragma unroll
    for (int qt = 0; qt < 4; ++qt) o[dt][qt] = (fx4){0.f, 0.f, 0.f, 0.f};
  float m_r[4] = {-3.0e38f, -3.0e38f, -3.0e38f, -3.0e38f};
  float l_r[4] = {0.f, 0.f, 0.f, 0.f};

  for (int kv0 = 0; kv0 < Skv; kv0 += 64) {
    __syncthreads();   // prev iteration's reads of Ks/Vt/Ps done
    // stage K tile [64][128]
    #pragma unroll
    for (int p = 0; p < 4; ++p) {
      int idx = tid + p * 256;
      int r = idx >> 4, f = idx & 15;
      uint4 v = *(const uint4*)&K[(size_t)(kv0 + r) * DIMC + cb + f * 8];
      *(uint4*)&Ks[SWZ(r, f * 8, 128)] = v;
    }
    // stage V transposed -> Vt[d][j]
    #pragma unroll
    for (int p = 0; p < 4; ++p) {
      int idx = tid + p * 256;
      int j = idx >> 4, f = idx & 15, d0 = f * 8;
      uint4 v = *(const uint4*)&V[(size_t)(kv0 + j) * DIMC + cb + d0];
      ushort u[8];
      u[0] = (ushort)(v.x & 0xFFFF); u[1] = (ushort)(v.x >> 16);
      u[2] = (ushort)(v.y & 0xFFFF); u[3] = (ushort)(v.y >> 16);
      u[4] = (ushort)(v.z & 0xFFFF); u[5] = (ushort)(v.z >> 16);
      u[6] = (ushort)(v.w & 0xFFFF); u[7] = (ushort)(v.w >> 16);
      #pragma unroll
      for (int i = 0; i < 8; ++i)
        Vt[SWZ(d0 + i, j, 64)] = u[i];
    }
    __syncthreads();

    // ---- QK^T: wave w computes S[16 rows][64 cols] ----
    fx4 s[4];
    #pragma unroll
    for (int n = 0; n < 4; ++n) s[n] = (fx4){0.f, 0.f, 0.f, 0.f};
    #pragma unroll
    for (int kt = 0; kt < 4; ++kt) {
      bfx8 aq = *(const bfx8*)&Qs[SWZ(w * 16 + lr, kt * 32 + lg * 8, 128)];
      #pragma unroll
      for (int n = 0; n < 4; ++n) {
        bfx8 bk = *(const bfx8*)&Ks[SWZ(n * 16 + lr, kt * 32 + lg * 8, 128)];
        s[n] = __builtin_amdgcn_mfma_f32_16x16x32_bf16(aq, bk, s[n], 0, 0, 0);
      }
    }
    // ---- softmax (rows q = w*16 + lg*4 + r; cols = n*16 + lr) ----
    #pragma unroll
    for (int n = 0; n < 4; ++n)
      #pragma unroll
      for (int r = 0; r < 4; ++r) s[n][r] *= ATTN_SCALE;
    float al[4];
    #pragma unroll
    for (int r = 0; r < 4; ++r) {
      float v0 = fmaxf(fmaxf(s[0][r], s[1][r]), fmaxf(s[2][r], s[3][r]));
      #pragma unroll
      for (int msk = 1; msk < 16; msk <<= 1) v0 = fmaxf(v0, __shfl_xor(v0, msk, 64));
      float nm = fmaxf(m_r[r], v0);
      al[r] = __expf(m_r[r] - nm);
      m_r[r] = nm;
      float sum = 0.f;
      #pragma unroll
      for (int n = 0; n < 4; ++n) {
        float pv = __expf(s[n][r] - nm);
        s[n][r] = pv;
        sum += pv;
      }
      #pragma unroll
      for (int msk = 1; msk < 16; msk <<= 1) sum += __shfl_xor(sum, msk, 64);
      l_r[r] = l_r[r] * al[r] + sum;
    }
    // write P (bf16) + alpha
    #pragma unroll
    for (int n = 0; n < 4; ++n)
      #pragma unroll
      for (int r = 0; r < 4; ++r)
        Ps[SWZ(w * 16 + lg * 4 + r, n * 16 + lr, 64)] = f2bf(s[n][r]);
    if (lr == 0) {
      #pragma unroll
      for (int r = 0; r < 4; ++r) aS[w * 16 + lg * 4 + r] = al[r];
    }
    __syncthreads();

    // ---- rescale O^T by alpha[q] (q = qt*16 + lr : uniform per lane) ----
    #pragma unroll
    for (int qt = 0; qt < 4; ++qt) {
      float a = aS[qt * 16 + lr];
      #pragma unroll
      for (int dt = 0; dt < 2; ++dt)
        #pragma unroll
        for (int r = 0; r < 4; ++r) o[dt][qt][r] *= a;
    }
    // ---- PV: wave w owns d in [w*32, w*32+32) ----
    #pragma unroll
    for (int js = 0; js < 2; ++js) {
      bfx8 av[2];
      #pragma unroll
      for (int dt = 0; dt < 2; ++dt)
        av[dt] = *(const bfx8*)&Vt[SWZ(w * 32 + dt * 16 + lr, js * 32 + lg * 8, 64)];
      #pragma unroll
      for (int qt = 0; qt < 4; ++qt) {
        bfx8 bp = *(const bfx8*)&Ps[SWZ(qt * 16 + lr, js * 32 + lg * 8, 64)];
        #pragma unroll
        for (int dt = 0; dt < 2; ++dt)
          o[dt][qt] = __builtin_amdgcn_mfma_f32_16x16x32_bf16(av[dt], bp, o[dt][qt], 0, 0, 0);
      }
    }
  }

  // ---- finalize: write l, normalize, transpose O^T -> Os (reuse Qs), store ----
  if (lr == 0) {
    #pragma unroll
    for (int r = 0; r < 4; ++r) lS[w * 16 + lg * 4 + r] = l_r[r];
  }
  __syncthreads();
  #pragma unroll
  for (int qt = 0; qt < 4; ++qt) {
    float inv = 1.0f / lS[qt * 16 + lr];
    int q = qt * 16 + lr;
    #pragma unroll
    for (int dt = 0; dt < 2; ++dt) {
      #pragma unroll
      for (int r = 0; r < 4; ++r) {
        int d = w * 32 + dt * 16 + lg * 4 + r;
        Qs[SWZ(q, d, 128)] = f2bf(o[dt][qt][r] * inv);
      }
    }
  }
  __syncthreads();
  #pragma unroll
  for (int p = 0; p < 4; ++p) {
    int idx = tid + p * 256;
    int r = idx >> 4, f = idx & 15;
    uint4 v = *(const uint4*)&Qs[SWZ(r, f * 8, 128)];
    *(uint4*)&O[(size_t)(q0 + r) * DIMC + cb + f * 8] = v;
  }
}

// ---------------- host side ----------------
static inline void mgemm_launch(int mode, const ushort* A, const float* W,
    const float* bias, const float* res, const float* evec, void* C,
    int M, int N, int K, hipStream_t s) {
  dim3 grid(N / 128, M / 128), blk(256);
  switch (mode) {
    case 0: mgemm_kernel<0><<<grid, blk, 0, s>>>(A, W, bias, res, evec, C, K, N); break;
    case 1: mgemm_kernel<1><<<grid, blk, 0, s>>>(A, W, bias, res, evec, C, K, N); break;
    case 2: mgemm_kernel<2><<<grid, blk, 0, s>>>(A, W, bias, res, evec, C, K, N); break;
    case 3: mgemm_kernel<3><<<grid, blk, 0, s>>>(A, W, bias, res, evec, C, K, N); break;
  }
}

extern "C" void kernel_launch(void* const* d_in, const int* in_sizes, int n_in,
                              void* d_out, int out_size, void* d_ws, size_t ws_size,
                              hipStream_t stream) {
  const float* x     = (const float*)d_in[0];
  const float* e     = (const float*)d_in[1];
  const float* ctx   = (const float*)d_in[2];
  const float* q_w   = (const float*)d_in[6];
  const float* q_b   = (const float*)d_in[7];
  const float* k_w   = (const float*)d_in[8];
  const float* k_b   = (const float*)d_in[9];
  const float* v_w   = (const float*)d_in[10];
  const float* v_b   = (const float*)d_in[11];
  const float* o_w   = (const float*)d_in[12];
  const float* o_b   = (const float*)d_in[13];
  const float* nq_w  = (const float*)d_in[14];
  const float* nk_w  = (const float*)d_in[15];
  const float* cq_w  = (const float*)d_in[16];
  const float* cq_b  = (const float*)d_in[17];
  const float* ck_w  = (const float*)d_in[18];
  const float* ck_b  = (const float*)d_in[19];
  const float* cv_w  = (const float*)d_in[20];
  const float* cv_b  = (const float*)d_in[21];
  const float* co_w  = (const float*)d_in[22];
  const float* co_b  = (const float*)d_in[23];
  const float* cnq_w = (const float*)d_in[24];
  const float* cnk_w = (const float*)d_in[25];
  const float* n3g   = (const float*)d_in[26];
  const float* n3b   = (const float*)d_in[27];
  const float* w1    = (const float*)d_in[28];
  const float* b1    = (const float*)d_in[29];
  const float* w2    = (const float*)d_in[30];
  const float* b2    = (const float*)d_in[31];
  const float* mod   = (const float*)d_in[32];
  const float* ang_f = (const float*)d_in[33];
  const float* ang_h = (const float*)d_in[34];
  const float* ang_w = (const float*)d_in[35];
  float* out = (float*)d_out;

  // ---- workspace layout (bytes), ~79 MB ----
  const size_t SB  = (size_t)SEQL * DIMC;
  char* w = (char*)d_ws;
  float*  em    = (float*)w;   w += 6 * DIMC * 4;
  float*  cs    = (float*)w;   w += (size_t)SEQL * 128 * 4;
  ushort* actbf = (ushort*)w;  w += SB * 2;                 // y / cx / y3
  ushort* Qbf   = (ushort*)w;  w += SB * 2;                 // q / cq   (hidden part 1)
  ushort* Kbf   = (ushort*)w;  w += SB * 2;                 // k / ck   (hidden part 2)
  ushort* Vbf   = (ushort*)w;  w += SB * 2;                 // v / cv   (hidden part 3)
  ushort* abf   = (ushort*)w;  w += SB * 2;                 // attn out (hidden part 4)
  float*  x2f   = (float*)w;   w += SB * 4;                 // x2, then x3 (in place)
  ushort* ctxbf = (ushort*)w;  w += (size_t)CTXL * CTXD * 2;
  ushort* hidden = Qbf;        // 2560*8192 bf16 aliases Qbf..abf
  const size_t need = (size_t)(w - (char*)d_ws);
  if (ws_size < need) return;

  const float* e0 = em + 0 * DIMC;
  const float* e1 = em + 1 * DIMC;
  const float* e2 = em + 2 * DIMC;
  const float* e3 = em + 3 * DIMC;
  const float* e4 = em + 4 * DIMC;
  const float* e5 = em + 5 * DIMC;

  em_kernel<<<48, 256, 0, stream>>>(e, mod, em);
  cs_kernel<<<640, 256, 0, stream>>>(ang_f, ang_h, ang_w, cs);
  castbf_kernel<<<2048, 256, 0, stream>>>(ctx, ctxbf, (CTXL * CTXD) / 4);

  // y = LN(x)*(1+e1)+e0 -> bf16
  ln_bf_kernel<<<SEQL, 256, 0, stream>>>(x, actbf, e1, e0, 1);

  // QKV projections (bf16 out)
  mgemm_launch(0, actbf, q_w, q_b, nullptr, nullptr, Qbf, SEQL, DIMC, DIMC, stream);
  mgemm_launch(0, actbf, k_w, k_b, nullptr, nullptr, Kbf, SEQL, DIMC, DIMC, stream);
  mgemm_launch(0, actbf, v_w, v_b, nullptr, nullptr, Vbf, SEQL, DIMC, DIMC, stream);

  // rmsnorm + rope on q,k (bf16 in-place)
  rms_rope_bf<<<SEQL, 256, 0, stream>>>(Qbf, nq_w, cs, 1);
  rms_rope_bf<<<SEQL, 256, 0, stream>>>(Kbf, nk_w, cs, 1);

  // self attention -> abf
  attn_mfma_kernel<<<dim3(SEQL / 64, NHEADS), 256, 0, stream>>>(Qbf, Kbf, Vbf, abf, SEQL);

  // x2 = x + (a @ o_w + o_b) * e2 -> f32
  mgemm_launch(2, abf, o_w, o_b, x, e2, x2f, SEQL, DIMC, DIMC, stream);

  // cx = LN(x2, g, b) -> bf16
  ln_bf_kernel<<<SEQL, 256, 0, stream>>>(x2f, actbf, n3g, n3b, 0);

  // cq (bf16) + rms
  mgemm_launch(0, actbf, cq_w, cq_b, nullptr, nullptr, Qbf, SEQL, DIMC, DIMC, stream);
  rms_rope_bf<<<SEQL, 256, 0, stream>>>(Qbf, cnq_w, cs, 0);

  // ck, cv from context (K = 4096)
  mgemm_launch(0, ctxbf, ck_w, ck_b, nullptr, nullptr, Kbf, CTXL, DIMC, CTXD, stream);
  rms_rope_bf<<<CTXL, 256, 0, stream>>>(Kbf, cnk_w, cs, 0);
  mgemm_launch(0, ctxbf, cv_w, cv_b, nullptr, nullptr, Vbf, CTXL, DIMC, CTXD, stream);

  // cross attention -> abf
  attn_mfma_kernel<<<dim3(SEQL / 64, NHEADS), 256, 0, stream>>>(Qbf, Kbf, Vbf, abf, CTXL);

  // x3 = x2 + (ca @ co_w + co_b) -> x2f in place
  mgemm_launch(3, abf, co_w, co_b, x2f, nullptr, x2f, SEQL, DIMC, DIMC, stream);

  // y3 = LN(x3)*(1+e4)+e3 -> bf16
  ln_bf_kernel<<<SEQL, 256, 0, stream>>>(x2f, actbf, e4, e3, 1);

  // FFN
  mgemm_launch(1, actbf, w1, b1, nullptr, nullptr, hidden, SEQL, FFND, DIMC, stream);
  mgemm_launch(2, hidden, w2, b2, x2f, e5, out, SEQL, DIMC, FFND, stream);
}

// Round 10
// 1594.288 us; speedup vs baseline: 4.7194x; 1.2979x over previous
//
#include <hip/hip_runtime.h>
#include <cstdint>

// ---------------- problem constants ----------------
#define SEQL     2560     // 4*20*32
#define DIMC     2048
#define NHEADS   16
#define HD       128
#define FFND     8192
#define CTXD     4096
#define CTXL     512
#define LN_EPS   1e-6f
#define ATTN_SCALE 0.08838834764831845f  // 128^-0.5

typedef __attribute__((ext_vector_type(8))) short bfx8;   // MFMA A/B frag (8 bf16)
typedef __attribute__((ext_vector_type(4))) float fx4;    // MFMA C/D frag

// ---------------- helpers ----------------
__device__ __forceinline__ float bf2f(ushort h) {
  union { uint u; float f; } c; c.u = ((uint)h) << 16; return c.f;
}
__device__ __forceinline__ ushort f2bf(float f) {
  union { float f; uint u; } c; c.f = f;
  uint u = c.u;
  return (ushort)((u + 0x7FFFu + ((u >> 16) & 1u)) >> 16);   // RNE
}
__device__ __forceinline__ float block_reduce_sum(float v, float* buf) {
  #pragma unroll
  for (int o = 32; o > 0; o >>= 1) v += __shfl_xor(v, o, 64);
  __syncthreads();
  if ((threadIdx.x & 63) == 0) buf[threadIdx.x >> 6] = v;
  __syncthreads();
  return buf[0] + buf[1] + buf[2] + buf[3];
}
__device__ __forceinline__ float gelu_tanh(float x) {
  float x3 = x * x * x;
  return 0.5f * x * (1.0f + tanhf(0.7978845608028654f * (x + 0.044715f * x3)));
}

// ---------------- tiny prep kernels ----------------
__global__ void em_kernel(const float* __restrict__ e, const float* __restrict__ mod,
                          float* __restrict__ em) {
  int g = blockIdx.x * 256 + threadIdx.x;
  if (g < 6 * DIMC) em[g] = e[g] + mod[g];
}

__global__ void cs_kernel(const float* __restrict__ af, const float* __restrict__ ah,
                          const float* __restrict__ aw, float* __restrict__ cs) {
  int g = blockIdx.x * 256 + threadIdx.x;   // 2560*64
  if (g >= SEQL * 64) return;
  int s = g >> 6, i = g & 63;
  int fi = s / 640, rem = s % 640, hi = rem >> 5, wi = rem & 31;
  float ang;
  if (i < 22)       ang = af[fi * 22 + i];          // cf = 22
  else if (i < 43)  ang = ah[hi * 21 + (i - 22)];   // ch = 21
  else              ang = aw[wi * 21 + (i - 43)];   // cw = 21
  cs[2 * g]     = cosf(ang);
  cs[2 * g + 1] = sinf(ang);
}

// float -> bf16 elementwise cast (ctx)
__global__ void castbf_kernel(const float* __restrict__ in, ushort* __restrict__ out, int n4) {
  int g = (blockIdx.x * 256 + threadIdx.x);
  if (g >= n4) return;
  float4 v = *(const float4*)&in[g * 4];
  uint2 p;
  p.x = (uint)f2bf(v.x) | ((uint)f2bf(v.y) << 16);
  p.y = (uint)f2bf(v.z) | ((uint)f2bf(v.w) << 16);
  *(uint2*)&out[g * 4] = p;
}

// ---------------- W transpose+cast: W fp32 [K][N] (ld=ldn) -> Wt bf16 [N][K] ----------------
// grid (N/64, K/64), 256 threads, 64x64 tile via LDS.
__global__ __launch_bounds__(256) void wtrans_kernel(const float* __restrict__ W,
    ushort* __restrict__ Wt, int K, int ldn) {
  __shared__ float t[64][65];
  const int tid = threadIdx.x;
  const int nt = blockIdx.x * 64, kt = blockIdx.y * 64;
  const int tx = tid & 15, ty = tid >> 4;
  #pragma unroll
  for (int s = 0; s < 4; ++s) {
    float4 v = *(const float4*)&W[(size_t)(kt + ty + 16 * s) * ldn + nt + tx * 4];
    t[ty + 16 * s][tx * 4 + 0] = v.x;
    t[ty + 16 * s][tx * 4 + 1] = v.y;
    t[ty + 16 * s][tx * 4 + 2] = v.z;
    t[ty + 16 * s][tx * 4 + 3] = v.w;
  }
  __syncthreads();
  const int r = tid >> 2, cb = (tid & 3) * 16;
  ushort u[16];
  #pragma unroll
  for (int i = 0; i < 16; ++i) u[i] = f2bf(t[cb + i][r]);
  uint4 a, b;
  a.x = (uint)u[0] | ((uint)u[1] << 16);  a.y = (uint)u[2] | ((uint)u[3] << 16);
  a.z = (uint)u[4] | ((uint)u[5] << 16);  a.w = (uint)u[6] | ((uint)u[7] << 16);
  b.x = (uint)u[8] | ((uint)u[9] << 16);  b.y = (uint)u[10] | ((uint)u[11] << 16);
  b.z = (uint)u[12] | ((uint)u[13] << 16); b.w = (uint)u[14] | ((uint)u[15] << 16);
  ushort* dst = Wt + (size_t)(nt + r) * K + kt + cb;
  *(uint4*)dst = a;
  *(uint4*)(dst + 8) = b;
}

// ---------------- LayerNorm (fp32 in -> bf16 out) ----------------
__global__ __launch_bounds__(256) void ln_bf_kernel(const float* __restrict__ x,
    ushort* __restrict__ y, const float* __restrict__ avec,
    const float* __restrict__ bvec, int addone) {
  __shared__ float buf[4];
  const int row = blockIdx.x, tid = threadIdx.x;
  const float* xr = x + (size_t)row * DIMC;
  float4 v0 = *(const float4*)&xr[4 * tid];
  float4 v1 = *(const float4*)&xr[1024 + 4 * tid];
  float s = v0.x + v0.y + v0.z + v0.w + v1.x + v1.y + v1.z + v1.w;
  s = block_reduce_sum(s, buf);
  float mean = s * (1.0f / 2048.0f);
  float d0[4] = {v0.x - mean, v0.y - mean, v0.z - mean, v0.w - mean};
  float d1[4] = {v1.x - mean, v1.y - mean, v1.z - mean, v1.w - mean};
  float ss = d0[0]*d0[0]+d0[1]*d0[1]+d0[2]*d0[2]+d0[3]*d0[3]
           + d1[0]*d1[0]+d1[1]*d1[1]+d1[2]*d1[2]+d1[3]*d1[3];
  ss = block_reduce_sum(ss, buf);
  float rstd = rsqrtf(ss * (1.0f / 2048.0f) + LN_EPS);
  float add = addone ? 1.0f : 0.0f;
  float4 a0 = *(const float4*)&avec[4 * tid];
  float4 a1 = *(const float4*)&avec[1024 + 4 * tid];
  float4 b0 = *(const float4*)&bvec[4 * tid];
  float4 b1 = *(const float4*)&bvec[1024 + 4 * tid];
  float o0[4], o1[4];
  o0[0] = d0[0]*rstd*(a0.x+add)+b0.x; o0[1] = d0[1]*rstd*(a0.y+add)+b0.y;
  o0[2] = d0[2]*rstd*(a0.z+add)+b0.z; o0[3] = d0[3]*rstd*(a0.w+add)+b0.w;
  o1[0] = d1[0]*rstd*(a1.x+add)+b1.x; o1[1] = d1[1]*rstd*(a1.y+add)+b1.y;
  o1[2] = d1[2]*rstd*(a1.z+add)+b1.z; o1[3] = d1[3]*rstd*(a1.w+add)+b1.w;
  ushort* yr = y + (size_t)row * DIMC;
  uint2 p0, p1;
  p0.x = (uint)f2bf(o0[0]) | ((uint)f2bf(o0[1]) << 16);
  p0.y = (uint)f2bf(o0[2]) | ((uint)f2bf(o0[3]) << 16);
  p1.x = (uint)f2bf(o1[0]) | ((uint)f2bf(o1[1]) << 16);
  p1.y = (uint)f2bf(o1[2]) | ((uint)f2bf(o1[3]) << 16);
  *(uint2*)&yr[4 * tid] = p0;
  *(uint2*)&yr[1024 + 4 * tid] = p1;
}

// ---------------- RMSNorm (bf16 in-place) + optional RoPE ----------------
__global__ __launch_bounds__(256) void rms_rope_bf(ushort* __restrict__ q,
    const float* __restrict__ wv, const float* __restrict__ cs, int do_rope) {
  __shared__ float buf[4];
  const int row = blockIdx.x, tid = threadIdx.x;
  ushort* xr = q + (size_t)row * DIMC + tid * 8;
  uint4 raw = *(const uint4*)xr;
  float v[8];
  v[0] = bf2f((ushort)(raw.x & 0xFFFF)); v[1] = bf2f((ushort)(raw.x >> 16));
  v[2] = bf2f((ushort)(raw.y & 0xFFFF)); v[3] = bf2f((ushort)(raw.y >> 16));
  v[4] = bf2f((ushort)(raw.z & 0xFFFF)); v[5] = bf2f((ushort)(raw.z >> 16));
  v[6] = bf2f((ushort)(raw.w & 0xFFFF)); v[7] = bf2f((ushort)(raw.w >> 16));
  float ss = 0.0f;
  #pragma unroll
  for (int i = 0; i < 8; ++i) ss += v[i] * v[i];
  ss = block_reduce_sum(ss, buf);
  float rr = rsqrtf(ss * (1.0f / 2048.0f) + LN_EPS);
  float4 w0 = *(const float4*)&wv[tid * 8];
  float4 w1 = *(const float4*)&wv[tid * 8 + 4];
  v[0] *= rr * w0.x; v[1] *= rr * w0.y; v[2] *= rr * w0.z; v[3] *= rr * w0.w;
  v[4] *= rr * w1.x; v[5] *= rr * w1.y; v[6] *= rr * w1.z; v[7] *= rr * w1.w;
  if (do_rope) {
    int p0 = (4 * tid) & 63;
    const float2* ct = (const float2*)cs + (size_t)row * 64 + p0;
    #pragma unroll
    for (int i = 0; i < 4; ++i) {
      float2 c = ct[i];
      float e = v[2 * i], o = v[2 * i + 1];
      v[2 * i]     = e * c.x - o * c.y;
      v[2 * i + 1] = e * c.y + o * c.x;
    }
  }
  uint4 out;
  out.x = (uint)f2bf(v[0]) | ((uint)f2bf(v[1]) << 16);
  out.y = (uint)f2bf(v[2]) | ((uint)f2bf(v[3]) << 16);
  out.z = (uint)f2bf(v[4]) | ((uint)f2bf(v[5]) << 16);
  out.w = (uint)f2bf(v[6]) | ((uint)f2bf(v[7]) << 16);
  *(uint4*)xr = out;
}

// ---------------- bf16 MFMA GEMM with pre-transposed bf16 W ----------------
// A [M][ldA] bf16, Wt [N][K] bf16 -> C epilogue.
// MODE 0: C(bf16) = acc + bias
// MODE 1: C(bf16) = gelu(acc + bias)
// MODE 2: C(f32)  = res + (acc + bias) * evec
// MODE 3: C(f32)  = res + (acc + bias)
// MODE 5: C(f32)  = acc                      (split-K part 1)
// MODE 6: C(f32)  = res + (C + acc + bias) * evec   (split-K part 2)
template<int MODE>
__global__ __launch_bounds__(256) void mgemmt_kernel(
    const ushort* __restrict__ A, const ushort* __restrict__ Wt,
    const float* __restrict__ bias, const float* __restrict__ res,
    const float* __restrict__ evec, void* __restrict__ Cout,
    int K, int ldA, int ldc) {
  __shared__ __align__(16) ushort As[128 * 40];
  __shared__ __align__(16) ushort Bs[128 * 40];
  const int tid = threadIdx.x;
  const int lane = tid & 63, wv = tid >> 6;
  const int wm = (wv >> 1) * 64, wn = (wv & 1) * 64;
  const int m0 = blockIdx.y * 128, n0 = blockIdx.x * 128;

  fx4 acc[4][4];
  #pragma unroll
  for (int i = 0; i < 4; ++i)
    #pragma unroll
    for (int j = 0; j < 4; ++j) acc[i][j] = (fx4){0.f, 0.f, 0.f, 0.f};

  const int sr = tid >> 1, sh = (tid & 1) * 16;
  const int lr = lane & 15, lk = (lane >> 4) * 8;
  const ushort* ga = A  + (size_t)(m0 + sr) * ldA + sh;
  const ushort* gb = Wt + (size_t)(n0 + sr) * K   + sh;

  for (int k0 = 0; k0 < K; k0 += 32) {
    uint4 va0 = *(const uint4*)(ga + k0);
    uint4 va1 = *(const uint4*)(ga + k0 + 8);
    uint4 vb0 = *(const uint4*)(gb + k0);
    uint4 vb1 = *(const uint4*)(gb + k0 + 8);
    __syncthreads();
    *(uint4*)&As[sr * 40 + sh]     = va0;
    *(uint4*)&As[sr * 40 + sh + 8] = va1;
    *(uint4*)&Bs[sr * 40 + sh]     = vb0;
    *(uint4*)&Bs[sr * 40 + sh + 8] = vb1;
    __syncthreads();

    bfx8 af[4], bf[4];
    #pragma unroll
    for (int mi = 0; mi < 4; ++mi)
      af[mi] = *(const bfx8*)&As[(wm + mi * 16 + lr) * 40 + lk];
    #pragma unroll
    for (int ni = 0; ni < 4; ++ni)
      bf[ni] = *(const bfx8*)&Bs[(wn + ni * 16 + lr) * 40 + lk];
    #pragma unroll
    for (int mi = 0; mi < 4; ++mi)
      #pragma unroll
      for (int ni = 0; ni < 4; ++ni)
        acc[mi][ni] = __builtin_amdgcn_mfma_f32_16x16x32_bf16(af[mi], bf[ni], acc[mi][ni], 0, 0, 0);
  }

  const int r4 = (lane >> 4) * 4;
  #pragma unroll
  for (int ni = 0; ni < 4; ++ni) {
    const int col = n0 + wn + ni * 16 + lr;
    float bv = 0.0f, ev = 0.0f;
    if constexpr (MODE != 5) bv = bias[col];
    if constexpr (MODE == 2 || MODE == 6) ev = evec[col];
    #pragma unroll
    for (int mi = 0; mi < 4; ++mi) {
      #pragma unroll
      for (int r = 0; r < 4; ++r) {
        const int row = m0 + wm + mi * 16 + r4 + r;
        const size_t off = (size_t)row * ldc + col;
        float v = acc[mi][ni][r];
        if constexpr (MODE == 0) { ((ushort*)Cout)[off] = f2bf(v + bv); }
        if constexpr (MODE == 1) { ((ushort*)Cout)[off] = f2bf(gelu_tanh(v + bv)); }
        if constexpr (MODE == 2) { ((float*)Cout)[off] = res[off] + (v + bv) * ev; }
        if constexpr (MODE == 3) { ((float*)Cout)[off] = res[off] + (v + bv); }
        if constexpr (MODE == 5) { ((float*)Cout)[off] = v; }
        if constexpr (MODE == 6) { ((float*)Cout)[off] = res[off] + (((float*)Cout)[off] + v + bv) * ev; }
      }
    }
  }
}

// ---------------- MFMA flash attention (bf16 in/out, fp32 accum) ----------------
// Per block: 1 head, 64 q rows, 4 waves. KV tiles of 64.
// QK^T: D[q][kpos] = mfma(A=Q rows, B=K rows).  PV: O^T[d][q] = mfma(A=Vt, B=P).
// Qs/Ks/Ps swizzle: (row&7).  Vt swizzle: ((row ^ row>>3)&7) — handles both the
// scatter-write pattern (lanes vary row>>3) and frag-read pattern (lanes vary row&7).
#define SWZ(row, col, stride) ((((row) * (stride)) + (col)) ^ (((row) & 7) << 3))
#define SWZV(row, col) ((((row) * 64) + (col)) ^ (((((row) >> 3) ^ (row)) & 7) << 3))
__global__ __launch_bounds__(256) void attn_mfma_kernel(
    const ushort* __restrict__ Q, const ushort* __restrict__ K,
    const ushort* __restrict__ V, ushort* __restrict__ O, int Skv) {
  __shared__ __align__(16) ushort Qs[64 * 128];   // reused as Os at the end
  __shared__ __align__(16) ushort Ks[64 * 128];
  __shared__ __align__(16) ushort Vt[128 * 64];
  __shared__ __align__(16) ushort Ps[64 * 64];
  __shared__ float aS[64];
  __shared__ float lS[64];

  const int tid = threadIdx.x;
  const int lane = tid & 63, w = tid >> 6;
  const int lr = lane & 15, lg = lane >> 4;
  const int q0 = blockIdx.x * 64;
  const int cb = blockIdx.y * HD;

  #pragma unroll
  for (int p = 0; p < 4; ++p) {
    int idx = tid + p * 256;
    int r = idx >> 4, f = idx & 15;
    uint4 v = *(const uint4*)&Q[(size_t)(q0 + r) * DIMC + cb + f * 8];
    *(uint4*)&Qs[SWZ(r, f * 8, 128)] = v;
  }

  fx4 o[2][4];
  #pragma unroll
  for (int dt = 0; dt < 2; ++dt)
    #pragma unroll
    for (int qt = 0; qt < 4; ++qt) o[dt][qt] = (fx4){0.f, 0.f, 0.f, 0.f};
  float m_r[4] = {-3.0e38f, -3.0e38f, -3.0e38f, -3.0e38f};
  float l_r[4] = {0.f, 0.f, 0.f, 0.f};

  for (int kv0 = 0; kv0 < Skv; kv0 += 64) {
    __syncthreads();
    #pragma unroll
    for (int p = 0; p < 4; ++p) {
      int idx = tid + p * 256;
      int r = idx >> 4, f = idx & 15;
      uint4 v = *(const uint4*)&K[(size_t)(kv0 + r) * DIMC + cb + f * 8];
      *(uint4*)&Ks[SWZ(r, f * 8, 128)] = v;
    }
    #pragma unroll
    for (int p = 0; p < 4; ++p) {
      int idx = tid + p * 256;
      int j = idx >> 4, f = idx & 15, d0 = f * 8;
      uint4 v = *(const uint4*)&V[(size_t)(kv0 + j) * DIMC + cb + d0];
      ushort u[8];
      u[0] = (ushort)(v.x & 0xFFFF); u[1] = (ushort)(v.x >> 16);
      u[2] = (ushort)(v.y & 0xFFFF); u[3] = (ushort)(v.y >> 16);
      u[4] = (ushort)(v.z & 0xFFFF); u[5] = (ushort)(v.z >> 16);
      u[6] = (ushort)(v.w & 0xFFFF); u[7] = (ushort)(v.w >> 16);
      #pragma unroll
      for (int i = 0; i < 8; ++i)
        Vt[SWZV(d0 + i, j)] = u[i];
    }
    __syncthreads();

    // ---- QK^T ----
    fx4 s[4];
    #pragma unroll
    for (int n = 0; n < 4; ++n) s[n] = (fx4){0.f, 0.f, 0.f, 0.f};
    #pragma unroll
    for (int kt = 0; kt < 4; ++kt) {
      bfx8 aq = *(const bfx8*)&Qs[SWZ(w * 16 + lr, kt * 32 + lg * 8, 128)];
      #pragma unroll
      for (int n = 0; n < 4; ++n) {
        bfx8 bk = *(const bfx8*)&Ks[SWZ(n * 16 + lr, kt * 32 + lg * 8, 128)];
        s[n] = __builtin_amdgcn_mfma_f32_16x16x32_bf16(aq, bk, s[n], 0, 0, 0);
      }
    }
    // ---- softmax ----
    #pragma unroll
    for (int n = 0; n < 4; ++n)
      #pragma unroll
      for (int r = 0; r < 4; ++r) s[n][r] *= ATTN_SCALE;
    float al[4];
    #pragma unroll
    for (int r = 0; r < 4; ++r) {
      float v0 = fmaxf(fmaxf(s[0][r], s[1][r]), fmaxf(s[2][r], s[3][r]));
      #pragma unroll
      for (int msk = 1; msk < 16; msk <<= 1) v0 = fmaxf(v0, __shfl_xor(v0, msk, 64));
      float nm = fmaxf(m_r[r], v0);
      al[r] = __expf(m_r[r] - nm);
      m_r[r] = nm;
      float sum = 0.f;
      #pragma unroll
      for (int n = 0; n < 4; ++n) {
        float pv = __expf(s[n][r] - nm);
        s[n][r] = pv;
        sum += pv;
      }
      #pragma unroll
      for (int msk = 1; msk < 16; msk <<= 1) sum += __shfl_xor(sum, msk, 64);
      l_r[r] = l_r[r] * al[r] + sum;
    }
    #pragma unroll
    for (int n = 0; n < 4; ++n)
      #pragma unroll
      for (int r = 0; r < 4; ++r)
        Ps[SWZ(w * 16 + lg * 4 + r, n * 16 + lr, 64)] = f2bf(s[n][r]);
    if (lr == 0) {
      #pragma unroll
      for (int r = 0; r < 4; ++r) aS[w * 16 + lg * 4 + r] = al[r];
    }
    __syncthreads();

    // ---- rescale + PV ----
    #pragma unroll
    for (int qt = 0; qt < 4; ++qt) {
      float a = aS[qt * 16 + lr];
      #pragma unroll
      for (int dt = 0; dt < 2; ++dt)
        #pragma unroll
        for (int r = 0; r < 4; ++r) o[dt][qt][r] *= a;
    }
    #pragma unroll
    for (int js = 0; js < 2; ++js) {
      bfx8 av[2];
      #pragma unroll
      for (int dt = 0; dt < 2; ++dt)
        av[dt] = *(const bfx8*)&Vt[SWZV(w * 32 + dt * 16 + lr, js * 32 + lg * 8)];
      #pragma unroll
      for (int qt = 0; qt < 4; ++qt) {
        bfx8 bp = *(const bfx8*)&Ps[SWZ(qt * 16 + lr, js * 32 + lg * 8, 64)];
        #pragma unroll
        for (int dt = 0; dt < 2; ++dt)
          o[dt][qt] = __builtin_amdgcn_mfma_f32_16x16x32_bf16(av[dt], bp, o[dt][qt], 0, 0, 0);
      }
    }
  }

  if (lr == 0) {
    #pragma unroll
    for (int r = 0; r < 4; ++r) lS[w * 16 + lg * 4 + r] = l_r[r];
  }
  __syncthreads();
  #pragma unroll
  for (int qt = 0; qt < 4; ++qt) {
    float inv = 1.0f / lS[qt * 16 + lr];
    int q = qt * 16 + lr;
    #pragma unroll
    for (int dt = 0; dt < 2; ++dt) {
      #pragma unroll
      for (int r = 0; r < 4; ++r) {
        int d = w * 32 + dt * 16 + lg * 4 + r;
        Qs[SWZ(q, d, 128)] = f2bf(o[dt][qt][r] * inv);
      }
    }
  }
  __syncthreads();
  #pragma unroll
  for (int p = 0; p < 4; ++p) {
    int idx = tid + p * 256;
    int r = idx >> 4, f = idx & 15;
    uint4 v = *(const uint4*)&Qs[SWZ(r, f * 8, 128)];
    *(uint4*)&O[(size_t)(q0 + r) * DIMC + cb + f * 8] = v;
  }
}

// ---------------- host side ----------------
static inline void mgemmt_launch(int mode, const ushort* A, const ushort* Wt,
    const float* bias, const float* res, const float* evec, void* C,
    int M, int N, int K, int ldA, int ldc, hipStream_t s) {
  dim3 grid(N / 128, M / 128), blk(256);
  switch (mode) {
    case 0: mgemmt_kernel<0><<<grid, blk, 0, s>>>(A, Wt, bias, res, evec, C, K, ldA, ldc); break;
    case 1: mgemmt_kernel<1><<<grid, blk, 0, s>>>(A, Wt, bias, res, evec, C, K, ldA, ldc); break;
    case 2: mgemmt_kernel<2><<<grid, blk, 0, s>>>(A, Wt, bias, res, evec, C, K, ldA, ldc); break;
    case 3: mgemmt_kernel<3><<<grid, blk, 0, s>>>(A, Wt, bias, res, evec, C, K, ldA, ldc); break;
    case 5: mgemmt_kernel<5><<<grid, blk, 0, s>>>(A, Wt, bias, res, evec, C, K, ldA, ldc); break;
    case 6: mgemmt_kernel<6><<<grid, blk, 0, s>>>(A, Wt, bias, res, evec, C, K, ldA, ldc); break;
  }
}
static inline void wtrans_launch(const float* W, ushort* Wt, int K, int N, int ldn,
                                 hipStream_t s) {
  wtrans_kernel<<<dim3(N / 64, K / 64), 256, 0, s>>>(W, Wt, K, ldn);
}

extern "C" void kernel_launch(void* const* d_in, const int* in_sizes, int n_in,
                              void* d_out, int out_size, void* d_ws, size_t ws_size,
                              hipStream_t stream) {
  const float* x     = (const float*)d_in[0];
  const float* e     = (const float*)d_in[1];
  const float* ctx   = (const float*)d_in[2];
  const float* q_w   = (const float*)d_in[6];
  const float* q_b   = (const float*)d_in[7];
  const float* k_w   = (const float*)d_in[8];
  const float* k_b   = (const float*)d_in[9];
  const float* v_w   = (const float*)d_in[10];
  const float* v_b   = (const float*)d_in[11];
  const float* o_w   = (const float*)d_in[12];
  const float* o_b   = (const float*)d_in[13];
  const float* nq_w  = (const float*)d_in[14];
  const float* nk_w  = (const float*)d_in[15];
  const float* cq_w  = (const float*)d_in[16];
  const float* cq_b  = (const float*)d_in[17];
  const float* ck_w  = (const float*)d_in[18];
  const float* ck_b  = (const float*)d_in[19];
  const float* cv_w  = (const float*)d_in[20];
  const float* cv_b  = (const float*)d_in[21];
  const float* co_w  = (const float*)d_in[22];
  const float* co_b  = (const float*)d_in[23];
  const float* cnq_w = (const float*)d_in[24];
  const float* cnk_w = (const float*)d_in[25];
  const float* n3g   = (const float*)d_in[26];
  const float* n3b   = (const float*)d_in[27];
  const float* w1    = (const float*)d_in[28];
  const float* b1    = (const float*)d_in[29];
  const float* w2    = (const float*)d_in[30];
  const float* b2    = (const float*)d_in[31];
  const float* mod   = (const float*)d_in[32];
  const float* ang_f = (const float*)d_in[33];
  const float* ang_h = (const float*)d_in[34];
  const float* ang_w = (const float*)d_in[35];
  float* out = (float*)d_out;

  // ---- workspace layout, ~92 MB total (< proven ws_size >= 93.63 MB) ----
  const size_t SB = (size_t)SEQL * DIMC;
  char* w = (char*)d_ws;
  float*  em    = (float*)w;   w += 6 * DIMC * 4;
  float*  cs    = (float*)w;   w += (size_t)SEQL * 128 * 4;
  ushort* actbf = (ushort*)w;  w += SB * 2;                 // y / cx / y3
  ushort* Qbf   = (ushort*)w;  w += SB * 2;
  ushort* Kbf   = (ushort*)w;  w += SB * 2;
  ushort* Vbf   = (ushort*)w;  w += SB * 2;
  ushort* abf   = (ushort*)w;  w += SB * 2;                 // attn out; ctxbf aliases this
  float*  x2f   = (float*)w;   w += SB * 4;                 // x2 then x3 (in place)
  ushort* Wt    = (ushort*)w;  w += (size_t)8388608 * 2;    // rotating W buffer (16.8 MB)
  ushort* ctxbf  = abf;        // alias: ctx bf16 lives in abf between o-proj and cross-attn
  ushort* hidden = Qbf;        // 2560x8192 bf16 spans Qbf..abf exactly
  const size_t need = (size_t)(w - (char*)d_ws);
  if (ws_size < need) return;

  const float* e0 = em + 0 * DIMC;
  const float* e1 = em + 1 * DIMC;
  const float* e2 = em + 2 * DIMC;
  const float* e3 = em + 3 * DIMC;
  const float* e4 = em + 4 * DIMC;
  const float* e5 = em + 5 * DIMC;

  em_kernel<<<48, 256, 0, stream>>>(e, mod, em);
  cs_kernel<<<640, 256, 0, stream>>>(ang_f, ang_h, ang_w, cs);

  // y = LN(x)*(1+e1)+e0 -> bf16
  ln_bf_kernel<<<SEQL, 256, 0, stream>>>(x, actbf, e1, e0, 1);

  // QKV projections
  wtrans_launch(q_w, Wt, DIMC, DIMC, DIMC, stream);
  mgemmt_launch(0, actbf, Wt, q_b, nullptr, nullptr, Qbf, SEQL, DIMC, DIMC, DIMC, DIMC, stream);
  wtrans_launch(k_w, Wt, DIMC, DIMC, DIMC, stream);
  mgemmt_launch(0, actbf, Wt, k_b, nullptr, nullptr, Kbf, SEQL, DIMC, DIMC, DIMC, DIMC, stream);
  wtrans_launch(v_w, Wt, DIMC, DIMC, DIMC, stream);
  mgemmt_launch(0, actbf, Wt, v_b, nullptr, nullptr, Vbf, SEQL, DIMC, DIMC, DIMC, DIMC, stream);

  rms_rope_bf<<<SEQL, 256, 0, stream>>>(Qbf, nq_w, cs, 1);
  rms_rope_bf<<<SEQL, 256, 0, stream>>>(Kbf, nk_w, cs, 1);

  // self attention -> abf
  attn_mfma_kernel<<<dim3(SEQL / 64, NHEADS), 256, 0, stream>>>(Qbf, Kbf, Vbf, abf, SEQL);

  // x2 = x + (a @ o_w + o_b) * e2 -> x2f
  wtrans_launch(o_w, Wt, DIMC, DIMC, DIMC, stream);
  mgemmt_launch(2, abf, Wt, o_b, x, e2, x2f, SEQL, DIMC, DIMC, DIMC, DIMC, stream);

  // ctx -> bf16 (into abf region, now dead until cross-attn writes it)
  castbf_kernel<<<2048, 256, 0, stream>>>(ctx, ctxbf, (CTXL * CTXD) / 4);

  // cx = LN(x2, g, b) -> actbf
  ln_bf_kernel<<<SEQL, 256, 0, stream>>>(x2f, actbf, n3g, n3b, 0);

  // cq + rms
  wtrans_launch(cq_w, Wt, DIMC, DIMC, DIMC, stream);
  mgemmt_launch(0, actbf, Wt, cq_b, nullptr, nullptr, Qbf, SEQL, DIMC, DIMC, DIMC, DIMC, stream);
  rms_rope_bf<<<SEQL, 256, 0, stream>>>(Qbf, cnq_w, cs, 0);

  // ck, cv from context (K = 4096)
  wtrans_launch(ck_w, Wt, CTXD, DIMC, DIMC, stream);
  mgemmt_launch(0, ctxbf, Wt, ck_b, nullptr, nullptr, Kbf, CTXL, DIMC, CTXD, CTXD, DIMC, stream);
  rms_rope_bf<<<CTXL, 256, 0, stream>>>(Kbf, cnk_w, cs, 0);
  wtrans_launch(cv_w, Wt, CTXD, DIMC, DIMC, stream);
  mgemmt_launch(0, ctxbf, Wt, cv_b, nullptr, nullptr, Vbf, CTXL, DIMC, CTXD, CTXD, DIMC, stream);

  // cross attention -> abf (ctxbf dead now)
  attn_mfma_kernel<<<dim3(SEQL / 64, NHEADS), 256, 0, stream>>>(Qbf, Kbf, Vbf, abf, CTXL);

  // x3 = x2 + (ca @ co_w + co_b) -> x2f in place
  wtrans_launch(co_w, Wt, DIMC, DIMC, DIMC, stream);
  mgemmt_launch(3, abf, Wt, co_b, x2f, nullptr, x2f, SEQL, DIMC, DIMC, DIMC, DIMC, stream);

  // y3 = LN(x3)*(1+e4)+e3 -> actbf
  ln_bf_kernel<<<SEQL, 256, 0, stream>>>(x2f, actbf, e4, e3, 1);

  // FFN: hidden = gelu(y3 @ w1 + b1), split by N-halves (Wt buffer limit)
  for (int h = 0; h < 2; ++h) {
    wtrans_launch(w1 + (size_t)h * 4096, Wt, DIMC, 4096, FFND, stream);
    mgemmt_launch(1, actbf, Wt, b1 + h * 4096, nullptr, nullptr, hidden + h * 4096,
                  SEQL, 4096, DIMC, DIMC, FFND, stream);
  }
  // out = x3 + (hidden @ w2 + b2) * e5, split by K-halves accumulating in d_out
  wtrans_launch(w2, Wt, 4096, DIMC, DIMC, stream);
  mgemmt_launch(5, hidden, Wt, nullptr, nullptr, nullptr, out,
                SEQL, DIMC, 4096, FFND, DIMC, stream);
  wtrans_launch(w2 + (size_t)4096 * DIMC, Wt, 4096, DIMC, DIMC, stream);
  mgemmt_launch(6, hidden + 4096, Wt, b2, x2f, e5, out,
                SEQL, DIMC, 4096, FFND, DIMC, stream);
}

// Round 11
// 1495.314 us; speedup vs baseline: 5.0318x; 1.0662x over previous
//
#include <hip/hip_runtime.h>
#include <cstdint>

// ---------------- problem constants ----------------
#define SEQL     2560     // 4*20*32
#define DIMC     2048
#define NHEADS   16
#define HD       128
#define FFND     8192
#define CTXD     4096
#define CTXL     512
#define LN_EPS   1e-6f
#define ATTN_SCALE 0.08838834764831845f  // 128^-0.5

typedef __attribute__((ext_vector_type(8))) short bfx8;   // MFMA A/B frag (8 bf16)
typedef __attribute__((ext_vector_type(4))) float fx4;    // MFMA C/D frag

// ---------------- helpers ----------------
__device__ __forceinline__ float bf2f(ushort h) {
  union { uint u; float f; } c; c.u = ((uint)h) << 16; return c.f;
}
__device__ __forceinline__ ushort f2bf(float f) {
  union { float f; uint u; } c; c.f = f;
  uint u = c.u;
  return (ushort)((u + 0x7FFFu + ((u >> 16) & 1u)) >> 16);   // RNE
}
__device__ __forceinline__ float block_reduce_sum(float v, float* buf) {
  #pragma unroll
  for (int o = 32; o > 0; o >>= 1) v += __shfl_xor(v, o, 64);
  __syncthreads();
  if ((threadIdx.x & 63) == 0) buf[threadIdx.x >> 6] = v;
  __syncthreads();
  return buf[0] + buf[1] + buf[2] + buf[3];
}
__device__ __forceinline__ float gelu_tanh(float x) {
  float x3 = x * x * x;
  return 0.5f * x * (1.0f + tanhf(0.7978845608028654f * (x + 0.044715f * x3)));
}
// async 16B global->LDS DMA (lds dest must be wave-uniform base; HW adds lane*16)
__device__ __forceinline__ void gload16(const ushort* g, ushort* l) {
  __builtin_amdgcn_global_load_lds(
      (const __attribute__((address_space(1))) uint*)g,
      (__attribute__((address_space(3))) uint*)l, 16, 0, 0);
}

// ---------------- tiny prep kernels ----------------
__global__ void em_kernel(const float* __restrict__ e, const float* __restrict__ mod,
                          float* __restrict__ em) {
  int g = blockIdx.x * 256 + threadIdx.x;
  if (g < 6 * DIMC) em[g] = e[g] + mod[g];
}

__global__ void cs_kernel(const float* __restrict__ af, const float* __restrict__ ah,
                          const float* __restrict__ aw, float* __restrict__ cs) {
  int g = blockIdx.x * 256 + threadIdx.x;   // 2560*64
  if (g >= SEQL * 64) return;
  int s = g >> 6, i = g & 63;
  int fi = s / 640, rem = s % 640, hi = rem >> 5, wi = rem & 31;
  float ang;
  if (i < 22)       ang = af[fi * 22 + i];          // cf = 22
  else if (i < 43)  ang = ah[hi * 21 + (i - 22)];   // ch = 21
  else              ang = aw[wi * 21 + (i - 43)];   // cw = 21
  cs[2 * g]     = cosf(ang);
  cs[2 * g + 1] = sinf(ang);
}

// float -> bf16 elementwise cast (ctx)
__global__ void castbf_kernel(const float* __restrict__ in, ushort* __restrict__ out, int n4) {
  int g = (blockIdx.x * 256 + threadIdx.x);
  if (g >= n4) return;
  float4 v = *(const float4*)&in[g * 4];
  uint2 p;
  p.x = (uint)f2bf(v.x) | ((uint)f2bf(v.y) << 16);
  p.y = (uint)f2bf(v.z) | ((uint)f2bf(v.w) << 16);
  *(uint2*)&out[g * 4] = p;
}

// ---------------- W transpose+cast: W fp32 [K][N] (ld=ldn) -> Wt bf16 [N][K] ----------------
__global__ __launch_bounds__(256) void wtrans_kernel(const float* __restrict__ W,
    ushort* __restrict__ Wt, int K, int ldn) {
  __shared__ float t[64][65];
  const int tid = threadIdx.x;
  const int nt = blockIdx.x * 64, kt = blockIdx.y * 64;
  const int tx = tid & 15, ty = tid >> 4;
  #pragma unroll
  for (int s = 0; s < 4; ++s) {
    float4 v = *(const float4*)&W[(size_t)(kt + ty + 16 * s) * ldn + nt + tx * 4];
    t[ty + 16 * s][tx * 4 + 0] = v.x;
    t[ty + 16 * s][tx * 4 + 1] = v.y;
    t[ty + 16 * s][tx * 4 + 2] = v.z;
    t[ty + 16 * s][tx * 4 + 3] = v.w;
  }
  __syncthreads();
  const int r = tid >> 2, cb = (tid & 3) * 16;
  ushort u[16];
  #pragma unroll
  for (int i = 0; i < 16; ++i) u[i] = f2bf(t[cb + i][r]);
  uint4 a, b;
  a.x = (uint)u[0] | ((uint)u[1] << 16);  a.y = (uint)u[2] | ((uint)u[3] << 16);
  a.z = (uint)u[4] | ((uint)u[5] << 16);  a.w = (uint)u[6] | ((uint)u[7] << 16);
  b.x = (uint)u[8] | ((uint)u[9] << 16);  b.y = (uint)u[10] | ((uint)u[11] << 16);
  b.z = (uint)u[12] | ((uint)u[13] << 16); b.w = (uint)u[14] | ((uint)u[15] << 16);
  ushort* dst = Wt + (size_t)(nt + r) * K + kt + cb;
  *(uint4*)dst = a;
  *(uint4*)(dst + 8) = b;
}

// ---------------- LayerNorm (fp32 in -> bf16 out) ----------------
__global__ __launch_bounds__(256) void ln_bf_kernel(const float* __restrict__ x,
    ushort* __restrict__ y, const float* __restrict__ avec,
    const float* __restrict__ bvec, int addone) {
  __shared__ float buf[4];
  const int row = blockIdx.x, tid = threadIdx.x;
  const float* xr = x + (size_t)row * DIMC;
  float4 v0 = *(const float4*)&xr[4 * tid];
  float4 v1 = *(const float4*)&xr[1024 + 4 * tid];
  float s = v0.x + v0.y + v0.z + v0.w + v1.x + v1.y + v1.z + v1.w;
  s = block_reduce_sum(s, buf);
  float mean = s * (1.0f / 2048.0f);
  float d0[4] = {v0.x - mean, v0.y - mean, v0.z - mean, v0.w - mean};
  float d1[4] = {v1.x - mean, v1.y - mean, v1.z - mean, v1.w - mean};
  float ss = d0[0]*d0[0]+d0[1]*d0[1]+d0[2]*d0[2]+d0[3]*d0[3]
           + d1[0]*d1[0]+d1[1]*d1[1]+d1[2]*d1[2]+d1[3]*d1[3];
  ss = block_reduce_sum(ss, buf);
  float rstd = rsqrtf(ss * (1.0f / 2048.0f) + LN_EPS);
  float add = addone ? 1.0f : 0.0f;
  float4 a0 = *(const float4*)&avec[4 * tid];
  float4 a1 = *(const float4*)&avec[1024 + 4 * tid];
  float4 b0 = *(const float4*)&bvec[4 * tid];
  float4 b1 = *(const float4*)&bvec[1024 + 4 * tid];
  float o0[4], o1[4];
  o0[0] = d0[0]*rstd*(a0.x+add)+b0.x; o0[1] = d0[1]*rstd*(a0.y+add)+b0.y;
  o0[2] = d0[2]*rstd*(a0.z+add)+b0.z; o0[3] = d0[3]*rstd*(a0.w+add)+b0.w;
  o1[0] = d1[0]*rstd*(a1.x+add)+b1.x; o1[1] = d1[1]*rstd*(a1.y+add)+b1.y;
  o1[2] = d1[2]*rstd*(a1.z+add)+b1.z; o1[3] = d1[3]*rstd*(a1.w+add)+b1.w;
  ushort* yr = y + (size_t)row * DIMC;
  uint2 p0, p1;
  p0.x = (uint)f2bf(o0[0]) | ((uint)f2bf(o0[1]) << 16);
  p0.y = (uint)f2bf(o0[2]) | ((uint)f2bf(o0[3]) << 16);
  p1.x = (uint)f2bf(o1[0]) | ((uint)f2bf(o1[1]) << 16);
  p1.y = (uint)f2bf(o1[2]) | ((uint)f2bf(o1[3]) << 16);
  *(uint2*)&yr[4 * tid] = p0;
  *(uint2*)&yr[1024 + 4 * tid] = p1;
}

// ---------------- RMSNorm (bf16 in-place) + optional RoPE ----------------
__global__ __launch_bounds__(256) void rms_rope_bf(ushort* __restrict__ q,
    const float* __restrict__ wv, const float* __restrict__ cs, int do_rope) {
  __shared__ float buf[4];
  const int row = blockIdx.x, tid = threadIdx.x;
  ushort* xr = q + (size_t)row * DIMC + tid * 8;
  uint4 raw = *(const uint4*)xr;
  float v[8];
  v[0] = bf2f((ushort)(raw.x & 0xFFFF)); v[1] = bf2f((ushort)(raw.x >> 16));
  v[2] = bf2f((ushort)(raw.y & 0xFFFF)); v[3] = bf2f((ushort)(raw.y >> 16));
  v[4] = bf2f((ushort)(raw.z & 0xFFFF)); v[5] = bf2f((ushort)(raw.z >> 16));
  v[6] = bf2f((ushort)(raw.w & 0xFFFF)); v[7] = bf2f((ushort)(raw.w >> 16));
  float ss = 0.0f;
  #pragma unroll
  for (int i = 0; i < 8; ++i) ss += v[i] * v[i];
  ss = block_reduce_sum(ss, buf);
  float rr = rsqrtf(ss * (1.0f / 2048.0f) + LN_EPS);
  float4 w0 = *(const float4*)&wv[tid * 8];
  float4 w1 = *(const float4*)&wv[tid * 8 + 4];
  v[0] *= rr * w0.x; v[1] *= rr * w0.y; v[2] *= rr * w0.z; v[3] *= rr * w0.w;
  v[4] *= rr * w1.x; v[5] *= rr * w1.y; v[6] *= rr * w1.z; v[7] *= rr * w1.w;
  if (do_rope) {
    int p0 = (4 * tid) & 63;
    const float2* ct = (const float2*)cs + (size_t)row * 64 + p0;
    #pragma unroll
    for (int i = 0; i < 4; ++i) {
      float2 c = ct[i];
      float e = v[2 * i], o = v[2 * i + 1];
      v[2 * i]     = e * c.x - o * c.y;
      v[2 * i + 1] = e * c.y + o * c.x;
    }
  }
  uint4 out;
  out.x = (uint)f2bf(v[0]) | ((uint)f2bf(v[1]) << 16);
  out.y = (uint)f2bf(v[2]) | ((uint)f2bf(v[3]) << 16);
  out.z = (uint)f2bf(v[4]) | ((uint)f2bf(v[5]) << 16);
  out.w = (uint)f2bf(v[6]) | ((uint)f2bf(v[7]) << 16);
  *(uint4*)xr = out;
}

// ---------------- bf16 MFMA GEMM: global_load_lds staging + XOR block swizzle ----------------
// A [M][ldA] bf16, Wt [N][K] bf16 -> C epilogue. 128x128 tile, BK=32, 4 waves 2x2.
// LDS tiles linear [128][32] (stride 64B). DMA: wave w inst j covers rows w*32+j*16..+16,
// lane l -> row w*32+j*16+(l>>2), storage block l&3. Swizzle: logical k-block b_log is
// stored at b_store = b_log ^ ((row>>1)&3); achieved by pre-swizzling the GLOBAL source
// column ((l&3)^((l>>3)&3), valid since (row>>1)&3 == (l>>3)&3), and XOR on frag reads.
// Read bank check: 16-lane group rows r..r+15 -> bank = 16(r&1)+4((r>>1)&3)^.. = 2-way (free).
// MODE 0: C(bf16)=acc+bias  1: gelu  2: res+(acc+b)*e  3: res+acc+b  5: acc  6: res+(C+acc+b)*e
template<int MODE>
__global__ __launch_bounds__(256) void mgemmt_kernel(
    const ushort* __restrict__ A, const ushort* __restrict__ Wt,
    const float* __restrict__ bias, const float* __restrict__ res,
    const float* __restrict__ evec, void* __restrict__ Cout,
    int K, int ldA, int ldc) {
  __shared__ __align__(16) ushort As[128 * 32];
  __shared__ __align__(16) ushort Bs[128 * 32];
  const int tid = threadIdx.x;
  const int lane = tid & 63, wv = tid >> 6;
  const int wm = (wv >> 1) * 64, wn = (wv & 1) * 64;
  const int m0 = blockIdx.y * 128, n0 = blockIdx.x * 128;

  fx4 acc[4][4];
  #pragma unroll
  for (int i = 0; i < 4; ++i)
    #pragma unroll
    for (int j = 0; j < 4; ++j) acc[i][j] = (fx4){0.f, 0.f, 0.f, 0.f};

  // per-lane DMA source mapping
  const int srow = wv * 32 + (lane >> 2);
  const int scol = ((lane & 3) ^ ((lane >> 3) & 3)) * 8;
  const ushort* gA0 = A  + (size_t)(m0 + srow) * ldA + scol;
  const ushort* gA1 = A  + (size_t)(m0 + srow + 16) * ldA + scol;
  const ushort* gB0 = Wt + (size_t)(n0 + srow) * K + scol;
  const ushort* gB1 = Wt + (size_t)(n0 + srow + 16) * K + scol;
  // wave-uniform LDS dest bases (1024B per inst per wave = 512 ushorts)
  ushort* aL0 = &As[wv * 1024];
  ushort* aL1 = &As[wv * 1024 + 512];
  ushort* bL0 = &Bs[wv * 1024];
  ushort* bL1 = &Bs[wv * 1024 + 512];

  const int lr = lane & 15, lg = lane >> 4;

  for (int k0 = 0; k0 < K; k0 += 32) {
    __syncthreads();                 // previous iteration's frag reads done
    gload16(gA0 + k0, aL0);
    gload16(gA1 + k0, aL1);
    gload16(gB0 + k0, bL0);
    gload16(gB1 + k0, bL1);
    __syncthreads();                 // compiler drains vmcnt before barrier -> tile ready

    bfx8 af[4], bf[4];
    #pragma unroll
    for (int mi = 0; mi < 4; ++mi) {
      const int ra = wm + mi * 16 + lr;
      af[mi] = *(const bfx8*)&As[ra * 32 + ((lg ^ ((ra >> 1) & 3)) * 8)];
    }
    #pragma unroll
    for (int ni = 0; ni < 4; ++ni) {
      const int rb = wn + ni * 16 + lr;
      bf[ni] = *(const bfx8*)&Bs[rb * 32 + ((lg ^ ((rb >> 1) & 3)) * 8)];
    }
    #pragma unroll
    for (int mi = 0; mi < 4; ++mi)
      #pragma unroll
      for (int ni = 0; ni < 4; ++ni)
        acc[mi][ni] = __builtin_amdgcn_mfma_f32_16x16x32_bf16(af[mi], bf[ni], acc[mi][ni], 0, 0, 0);
  }

  const int r4 = (lane >> 4) * 4;
  #pragma unroll
  for (int ni = 0; ni < 4; ++ni) {
    const int col = n0 + wn + ni * 16 + lr;
    float bv = 0.0f, ev = 0.0f;
    if constexpr (MODE != 5) bv = bias[col];
    if constexpr (MODE == 2 || MODE == 6) ev = evec[col];
    #pragma unroll
    for (int mi = 0; mi < 4; ++mi) {
      #pragma unroll
      for (int r = 0; r < 4; ++r) {
        const int row = m0 + wm + mi * 16 + r4 + r;
        const size_t off = (size_t)row * ldc + col;
        float v = acc[mi][ni][r];
        if constexpr (MODE == 0) { ((ushort*)Cout)[off] = f2bf(v + bv); }
        if constexpr (MODE == 1) { ((ushort*)Cout)[off] = f2bf(gelu_tanh(v + bv)); }
        if constexpr (MODE == 2) { ((float*)Cout)[off] = res[off] + (v + bv) * ev; }
        if constexpr (MODE == 3) { ((float*)Cout)[off] = res[off] + (v + bv); }
        if constexpr (MODE == 5) { ((float*)Cout)[off] = v; }
        if constexpr (MODE == 6) { ((float*)Cout)[off] = res[off] + (((float*)Cout)[off] + v + bv) * ev; }
      }
    }
  }
}

// ---------------- MFMA flash attention (unchanged from round 10) ----------------
#define SWZ(row, col, stride) ((((row) * (stride)) + (col)) ^ (((row) & 7) << 3))
#define SWZV(row, col) ((((row) * 64) + (col)) ^ (((((row) >> 3) ^ (row)) & 7) << 3))
__global__ __launch_bounds__(256) void attn_mfma_kernel(
    const ushort* __restrict__ Q, const ushort* __restrict__ K,
    const ushort* __restrict__ V, ushort* __restrict__ O, int Skv) {
  __shared__ __align__(16) ushort Qs[64 * 128];   // reused as Os at the end
  __shared__ __align__(16) ushort Ks[64 * 128];
  __shared__ __align__(16) ushort Vt[128 * 64];
  __shared__ __align__(16) ushort Ps[64 * 64];
  __shared__ float aS[64];
  __shared__ float lS[64];

  const int tid = threadIdx.x;
  const int lane = tid & 63, w = tid >> 6;
  const int lr = lane & 15, lg = lane >> 4;
  const int q0 = blockIdx.x * 64;
  const int cb = blockIdx.y * HD;

  #pragma unroll
  for (int p = 0; p < 4; ++p) {
    int idx = tid + p * 256;
    int r = idx >> 4, f = idx & 15;
    uint4 v = *(const uint4*)&Q[(size_t)(q0 + r) * DIMC + cb + f * 8];
    *(uint4*)&Qs[SWZ(r, f * 8, 128)] = v;
  }

  fx4 o[2][4];
  #pragma unroll
  for (int dt = 0; dt < 2; ++dt)
    #pragma unroll
    for (int qt = 0; qt < 4; ++qt) o[dt][qt] = (fx4){0.f, 0.f, 0.f, 0.f};
  float m_r[4] = {-3.0e38f, -3.0e38f, -3.0e38f, -3.0e38f};
  float l_r[4] = {0.f, 0.f, 0.f, 0.f};

  for (int kv0 = 0; kv0 < Skv; kv0 += 64) {
    __syncthreads();
    #pragma unroll
    for (int p = 0; p < 4; ++p) {
      int idx = tid + p * 256;
      int r = idx >> 4, f = idx & 15;
      uint4 v = *(const uint4*)&K[(size_t)(kv0 + r) * DIMC + cb + f * 8];
      *(uint4*)&Ks[SWZ(r, f * 8, 128)] = v;
    }
    #pragma unroll
    for (int p = 0; p < 4; ++p) {
      int idx = tid + p * 256;
      int j = idx >> 4, f = idx & 15, d0 = f * 8;
      uint4 v = *(const uint4*)&V[(size_t)(kv0 + j) * DIMC + cb + d0];
      ushort u[8];
      u[0] = (ushort)(v.x & 0xFFFF); u[1] = (ushort)(v.x >> 16);
      u[2] = (ushort)(v.y & 0xFFFF); u[3] = (ushort)(v.y >> 16);
      u[4] = (ushort)(v.z & 0xFFFF); u[5] = (ushort)(v.z >> 16);
      u[6] = (ushort)(v.w & 0xFFFF); u[7] = (ushort)(v.w >> 16);
      #pragma unroll
      for (int i = 0; i < 8; ++i)
        Vt[SWZV(d0 + i, j)] = u[i];
    }
    __syncthreads();

    // ---- QK^T ----
    fx4 s[4];
    #pragma unroll
    for (int n = 0; n < 4; ++n) s[n] = (fx4){0.f, 0.f, 0.f, 0.f};
    #pragma unroll
    for (int kt = 0; kt < 4; ++kt) {
      bfx8 aq = *(const bfx8*)&Qs[SWZ(w * 16 + lr, kt * 32 + lg * 8, 128)];
      #pragma unroll
      for (int n = 0; n < 4; ++n) {
        bfx8 bk = *(const bfx8*)&Ks[SWZ(n * 16 + lr, kt * 32 + lg * 8, 128)];
        s[n] = __builtin_amdgcn_mfma_f32_16x16x32_bf16(aq, bk, s[n], 0, 0, 0);
      }
    }
    // ---- softmax ----
    #pragma unroll
    for (int n = 0; n < 4; ++n)
      #pragma unroll
      for (int r = 0; r < 4; ++r) s[n][r] *= ATTN_SCALE;
    float al[4];
    #pragma unroll
    for (int r = 0; r < 4; ++r) {
      float v0 = fmaxf(fmaxf(s[0][r], s[1][r]), fmaxf(s[2][r], s[3][r]));
      #pragma unroll
      for (int msk = 1; msk < 16; msk <<= 1) v0 = fmaxf(v0, __shfl_xor(v0, msk, 64));
      float nm = fmaxf(m_r[r], v0);
      al[r] = __expf(m_r[r] - nm);
      m_r[r] = nm;
      float sum = 0.f;
      #pragma unroll
      for (int n = 0; n < 4; ++n) {
        float pv = __expf(s[n][r] - nm);
        s[n][r] = pv;
        sum += pv;
      }
      #pragma unroll
      for (int msk = 1; msk < 16; msk <<= 1) sum += __shfl_xor(sum, msk, 64);
      l_r[r] = l_r[r] * al[r] + sum;
    }
    #pragma unroll
    for (int n = 0; n < 4; ++n)
      #pragma unroll
      for (int r = 0; r < 4; ++r)
        Ps[SWZ(w * 16 + lg * 4 + r, n * 16 + lr, 64)] = f2bf(s[n][r]);
    if (lr == 0) {
      #pragma unroll
      for (int r = 0; r < 4; ++r) aS[w * 16 + lg * 4 + r] = al[r];
    }
    __syncthreads();

    // ---- rescale + PV ----
    #pragma unroll
    for (int qt = 0; qt < 4; ++qt) {
      float a = aS[qt * 16 + lr];
      #pragma unroll
      for (int dt = 0; dt < 2; ++dt)
        #pragma unroll
        for (int r = 0; r < 4; ++r) o[dt][qt][r] *= a;
    }
    #pragma unroll
    for (int js = 0; js < 2; ++js) {
      bfx8 av[2];
      #pragma unroll
      for (int dt = 0; dt < 2; ++dt)
        av[dt] = *(const bfx8*)&Vt[SWZV(w * 32 + dt * 16 + lr, js * 32 + lg * 8)];
      #pragma unroll
      for (int qt = 0; qt < 4; ++qt) {
        bfx8 bp = *(const bfx8*)&Ps[SWZ(qt * 16 + lr, js * 32 + lg * 8, 64)];
        #pragma unroll
        for (int dt = 0; dt < 2; ++dt)
          o[dt][qt] = __builtin_amdgcn_mfma_f32_16x16x32_bf16(av[dt], bp, o[dt][qt], 0, 0, 0);
      }
    }
  }

  if (lr == 0) {
    #pragma unroll
    for (int r = 0; r < 4; ++r) lS[w * 16 + lg * 4 + r] = l_r[r];
  }
  __syncthreads();
  #pragma unroll
  for (int qt = 0; qt < 4; ++qt) {
    float inv = 1.0f / lS[qt * 16 + lr];
    int q = qt * 16 + lr;
    #pragma unroll
    for (int dt = 0; dt < 2; ++dt) {
      #pragma unroll
      for (int r = 0; r < 4; ++r) {
        int d = w * 32 + dt * 16 + lg * 4 + r;
        Qs[SWZ(q, d, 128)] = f2bf(o[dt][qt][r] * inv);
      }
    }
  }
  __syncthreads();
  #pragma unroll
  for (int p = 0; p < 4; ++p) {
    int idx = tid + p * 256;
    int r = idx >> 4, f = idx & 15;
    uint4 v = *(const uint4*)&Qs[SWZ(r, f * 8, 128)];
    *(uint4*)&O[(size_t)(q0 + r) * DIMC + cb + f * 8] = v;
  }
}

// ---------------- host side ----------------
static inline void mgemmt_launch(int mode, const ushort* A, const ushort* Wt,
    const float* bias, const float* res, const float* evec, void* C,
    int M, int N, int K, int ldA, int ldc, hipStream_t s) {
  dim3 grid(N / 128, M / 128), blk(256);
  switch (mode) {
    case 0: mgemmt_kernel<0><<<grid, blk, 0, s>>>(A, Wt, bias, res, evec, C, K, ldA, ldc); break;
    case 1: mgemmt_kernel<1><<<grid, blk, 0, s>>>(A, Wt, bias, res, evec, C, K, ldA, ldc); break;
    case 2: mgemmt_kernel<2><<<grid, blk, 0, s>>>(A, Wt, bias, res, evec, C, K, ldA, ldc); break;
    case 3: mgemmt_kernel<3><<<grid, blk, 0, s>>>(A, Wt, bias, res, evec, C, K, ldA, ldc); break;
    case 5: mgemmt_kernel<5><<<grid, blk, 0, s>>>(A, Wt, bias, res, evec, C, K, ldA, ldc); break;
    case 6: mgemmt_kernel<6><<<grid, blk, 0, s>>>(A, Wt, bias, res, evec, C, K, ldA, ldc); break;
  }
}
static inline void wtrans_launch(const float* W, ushort* Wt, int K, int N, int ldn,
                                 hipStream_t s) {
  wtrans_kernel<<<dim3(N / 64, K / 64), 256, 0, s>>>(W, Wt, K, ldn);
}

extern "C" void kernel_launch(void* const* d_in, const int* in_sizes, int n_in,
                              void* d_out, int out_size, void* d_ws, size_t ws_size,
                              hipStream_t stream) {
  const float* x     = (const float*)d_in[0];
  const float* e     = (const float*)d_in[1];
  const float* ctx   = (const float*)d_in[2];
  const float* q_w   = (const float*)d_in[6];
  const float* q_b   = (const float*)d_in[7];
  const float* k_w   = (const float*)d_in[8];
  const float* k_b   = (const float*)d_in[9];
  const float* v_w   = (const float*)d_in[10];
  const float* v_b   = (const float*)d_in[11];
  const float* o_w   = (const float*)d_in[12];
  const float* o_b   = (const float*)d_in[13];
  const float* nq_w  = (const float*)d_in[14];
  const float* nk_w  = (const float*)d_in[15];
  const float* cq_w  = (const float*)d_in[16];
  const float* cq_b  = (const float*)d_in[17];
  const float* ck_w  = (const float*)d_in[18];
  const float* ck_b  = (const float*)d_in[19];
  const float* cv_w  = (const float*)d_in[20];
  const float* cv_b  = (const float*)d_in[21];
  const float* co_w  = (const float*)d_in[22];
  const float* co_b  = (const float*)d_in[23];
  const float* cnq_w = (const float*)d_in[24];
  const float* cnk_w = (const float*)d_in[25];
  const float* n3g   = (const float*)d_in[26];
  const float* n3b   = (const float*)d_in[27];
  const float* w1    = (const float*)d_in[28];
  const float* b1    = (const float*)d_in[29];
  const float* w2    = (const float*)d_in[30];
  const float* b2    = (const float*)d_in[31];
  const float* mod   = (const float*)d_in[32];
  const float* ang_f = (const float*)d_in[33];
  const float* ang_h = (const float*)d_in[34];
  const float* ang_w = (const float*)d_in[35];
  float* out = (float*)d_out;

  // ---- workspace layout, ~92 MB total (< proven ws_size >= 93.63 MB) ----
  const size_t SB = (size_t)SEQL * DIMC;
  char* w = (char*)d_ws;
  float*  em    = (float*)w;   w += 6 * DIMC * 4;
  float*  cs    = (float*)w;   w += (size_t)SEQL * 128 * 4;
  ushort* actbf = (ushort*)w;  w += SB * 2;                 // y / cx / y3
  ushort* Qbf   = (ushort*)w;  w += SB * 2;
  ushort* Kbf   = (ushort*)w;  w += SB * 2;
  ushort* Vbf   = (ushort*)w;  w += SB * 2;
  ushort* abf   = (ushort*)w;  w += SB * 2;                 // attn out; ctxbf aliases this
  float*  x2f   = (float*)w;   w += SB * 4;                 // x2 then x3 (in place)
  ushort* Wt    = (ushort*)w;  w += (size_t)8388608 * 2;    // rotating W buffer (16.8 MB)
  ushort* ctxbf  = abf;        // alias: ctx bf16 lives in abf between o-proj and cross-attn
  ushort* hidden = Qbf;        // 2560x8192 bf16 spans Qbf..abf exactly
  const size_t need = (size_t)(w - (char*)d_ws);
  if (ws_size < need) return;

  const float* e0 = em + 0 * DIMC;
  const float* e1 = em + 1 * DIMC;
  const float* e2 = em + 2 * DIMC;
  const float* e3 = em + 3 * DIMC;
  const float* e4 = em + 4 * DIMC;
  const float* e5 = em + 5 * DIMC;

  em_kernel<<<48, 256, 0, stream>>>(e, mod, em);
  cs_kernel<<<640, 256, 0, stream>>>(ang_f, ang_h, ang_w, cs);

  // y = LN(x)*(1+e1)+e0 -> bf16
  ln_bf_kernel<<<SEQL, 256, 0, stream>>>(x, actbf, e1, e0, 1);

  // QKV projections
  wtrans_launch(q_w, Wt, DIMC, DIMC, DIMC, stream);
  mgemmt_launch(0, actbf, Wt, q_b, nullptr, nullptr, Qbf, SEQL, DIMC, DIMC, DIMC, DIMC, stream);
  wtrans_launch(k_w, Wt, DIMC, DIMC, DIMC, stream);
  mgemmt_launch(0, actbf, Wt, k_b, nullptr, nullptr, Kbf, SEQL, DIMC, DIMC, DIMC, DIMC, stream);
  wtrans_launch(v_w, Wt, DIMC, DIMC, DIMC, stream);
  mgemmt_launch(0, actbf, Wt, v_b, nullptr, nullptr, Vbf, SEQL, DIMC, DIMC, DIMC, DIMC, stream);

  rms_rope_bf<<<SEQL, 256, 0, stream>>>(Qbf, nq_w, cs, 1);
  rms_rope_bf<<<SEQL, 256, 0, stream>>>(Kbf, nk_w, cs, 1);

  // self attention -> abf
  attn_mfma_kernel<<<dim3(SEQL / 64, NHEADS), 256, 0, stream>>>(Qbf, Kbf, Vbf, abf, SEQL);

  // x2 = x + (a @ o_w + o_b) * e2 -> x2f
  wtrans_launch(o_w, Wt, DIMC, DIMC, DIMC, stream);
  mgemmt_launch(2, abf, Wt, o_b, x, e2, x2f, SEQL, DIMC, DIMC, DIMC, DIMC, stream);

  // ctx -> bf16 (into abf region, now dead until cross-attn writes it)
  castbf_kernel<<<2048, 256, 0, stream>>>(ctx, ctxbf, (CTXL * CTXD) / 4);

  // cx = LN(x2, g, b) -> actbf
  ln_bf_kernel<<<SEQL, 256, 0, stream>>>(x2f, actbf, n3g, n3b, 0);

  // cq + rms
  wtrans_launch(cq_w, Wt, DIMC, DIMC, DIMC, stream);
  mgemmt_launch(0, actbf, Wt, cq_b, nullptr, nullptr, Qbf, SEQL, DIMC, DIMC, DIMC, DIMC, stream);
  rms_rope_bf<<<SEQL, 256, 0, stream>>>(Qbf, cnq_w, cs, 0);

  // ck, cv from context (K = 4096)
  wtrans_launch(ck_w, Wt, CTXD, DIMC, DIMC, stream);
  mgemmt_launch(0, ctxbf, Wt, ck_b, nullptr, nullptr, Kbf, CTXL, DIMC, CTXD, CTXD, DIMC, stream);
  rms_rope_bf<<<CTXL, 256, 0, stream>>>(Kbf, cnk_w, cs, 0);
  wtrans_launch(cv_w, Wt, CTXD, DIMC, DIMC, stream);
  mgemmt_launch(0, ctxbf, Wt, cv_b, nullptr, nullptr, Vbf, CTXL, DIMC, CTXD, CTXD, DIMC, stream);

  // cross attention -> abf (ctxbf dead now)
  attn_mfma_kernel<<<dim3(SEQL / 64, NHEADS), 256, 0, stream>>>(Qbf, Kbf, Vbf, abf, CTXL);

  // x3 = x2 + (ca @ co_w + co_b) -> x2f in place
  wtrans_launch(co_w, Wt, DIMC, DIMC, DIMC, stream);
  mgemmt_launch(3, abf, Wt, co_b, x2f, nullptr, x2f, SEQL, DIMC, DIMC, DIMC, DIMC, stream);

  // y3 = LN(x3)*(1+e4)+e3 -> actbf
  ln_bf_kernel<<<SEQL, 256, 0, stream>>>(x2f, actbf, e4, e3, 1);

  // FFN: hidden = gelu(y3 @ w1 + b1), split by N-halves (Wt buffer limit)
  for (int h = 0; h < 2; ++h) {
    wtrans_launch(w1 + (size_t)h * 4096, Wt, DIMC, 4096, FFND, stream);
    mgemmt_launch(1, actbf, Wt, b1 + h * 4096, nullptr, nullptr, hidden + h * 4096,
                  SEQL, 4096, DIMC, DIMC, FFND, stream);
  }
  // out = x3 + (hidden @ w2 + b2) * e5, split by K-halves accumulating in d_out
  wtrans_launch(w2, Wt, 4096, DIMC, DIMC, stream);
  mgemmt_launch(5, hidden, Wt, nullptr, nullptr, nullptr, out,
                SEQL, DIMC, 4096, FFND, DIMC, stream);
  wtrans_launch(w2 + (size_t)4096 * DIMC, Wt, 4096, DIMC, DIMC, stream);
  mgemmt_launch(6, hidden + 4096, Wt, b2, x2f, e5, out,
                SEQL, DIMC, 4096, FFND, DIMC, stream);
}